// Round 6
// baseline (2361.103 us; speedup 1.0000x reference)
//
#include <hip/hip_runtime.h>
#include <hip/hip_bf16.h>
#include <cstddef>

typedef __hip_bfloat16 bf16;
typedef __bf16 bfv8 __attribute__((ext_vector_type(8)));
typedef float f4 __attribute__((ext_vector_type(4)));

#define EPSN 1e-5f
#define SQRT3_INV 0.57735026918962576f
#define SQRT2_INV 0.70710678118654752f

__device__ __forceinline__ float b2f(bf16 x) { return __bfloat162float(x); }

template<int BF> __device__ __forceinline__ float ldf(const void* p, size_t i) {
    if (BF) return __bfloat162float(((const bf16*)p)[i]);
    return ((const float*)p)[i];
}
template<int BF> __device__ __forceinline__ void stf(void* p, size_t i, float v) {
    if (BF) ((bf16*)p)[i] = __float2bfloat16(v);
    else    ((float*)p)[i] = v;
}

__device__ __forceinline__ float wave_sum64(float x) {
    #pragma unroll
    for (int m = 1; m < 64; m <<= 1) x += __shfl_xor(x, m, 64);
    return x;
}

__device__ __forceinline__ f4 mf(bfv8 a, bfv8 b, f4 c) {
    return __builtin_amdgcn_mfma_f32_16x16x32_bf16(a, b, c, 0, 0, 0);
}

// ---------------- Sniffer ----------------
__global__ __launch_bounds__(256) void k_sniff(const void* node, const void* eidx, int* flags)
{
    int t = threadIdx.x;
    __shared__ int cnt;
    __shared__ unsigned orr;
    if (t == 0) { cnt = 0; orr = 0u; }
    __syncthreads();
    unsigned w  = ((const unsigned*)node)[t];
    unsigned lo = w & 0xFFFFu;
    int e_lo = (int)((lo >> 7) & 0xFF);
    if (e_lo >= 96 && e_lo <= 140) atomicAdd(&cnt, 1);
    unsigned odd = ((const unsigned*)eidx)[2 * t + 1];
    atomicOr(&orr, odd);
    __syncthreads();
    if (t == 0) {
        flags[0] = (cnt >= 128) ? 1 : 0;   // 1 = bf16 inputs
        flags[1] = (orr == 0u) ? 1 : 0;    // 1 = int64 edge_index
    }
}

__global__ __launch_bounds__(256) void k_zero(float* p, int n)
{
    int i = blockIdx.x * 256 + threadIdx.x;
    if (i < n) p[i] = 0.f;
}

// ---------------- Prep: transpose weights to bf16 [n][k] ----------------
template<int BF>
__global__ __launch_bounds__(256) void k_prep(
    const void* __restrict__ Walpha, const void* __restrict__ Wsval, const void* __restrict__ Wsvlin,
    const void* __restrict__ Wvval, const void* __restrict__ Wvvlin, const void* __restrict__ Wg,
    const void* __restrict__ Wrbf, const void* __restrict__ adot,
    const void* __restrict__ w2ss, const void* __restrict__ w2sv, const void* __restrict__ w2vs,
    const void* __restrict__ w2vv0, const void* __restrict__ w2vv1,
    bf16* __restrict__ WalphaT, bf16* __restrict__ WsvalT, bf16* __restrict__ WsvlinT,
    bf16* __restrict__ WvvalT, bf16* __restrict__ WvvlinT, bf16* __restrict__ WgT,
    bf16* __restrict__ WrbfT, bf16* __restrict__ adotB, bf16* __restrict__ w2B,
    const int* __restrict__ flags)
{
    if (flags[0] != BF) return;
    int t = threadIdx.x + blockIdx.x * 256;
    int T = gridDim.x * 256;
    for (int i = t; i < 96 * 64; i += T) {
        int c = i >> 6, n = i & 63;
        WalphaT[n * 96 + c] = __float2bfloat16(ldf<BF>(Walpha, i));
        WsvalT [n * 96 + c] = __float2bfloat16(ldf<BF>(Wsval,  i));
        WsvlinT[n * 96 + c] = __float2bfloat16(ldf<BF>(Wsvlin, i));
    }
    for (int i = t; i < 128 * 32; i += T) {
        int c = i >> 5, n = i & 31;
        WvvalT [n * 128 + c] = __float2bfloat16(ldf<BF>(Wvval,  i));
        WvvlinT[n * 128 + c] = __float2bfloat16(ldf<BF>(Wvvlin, i));
    }
    for (int i = t; i < 64 * 32; i += T) {
        int c = i >> 5, n = i & 31;
        WgT[n * 64 + c] = __float2bfloat16(ldf<BF>(Wg, i));
    }
    for (int i = t; i < 16 * 224; i += T) {
        int b = i / 224, c = i - b * 224;
        WrbfT[c * 16 + b] = __float2bfloat16(ldf<BF>(Wrbf, i));
    }
    if (t < 64) adotB[t] = __float2bfloat16(ldf<BF>(adot, t));
    if (t < 64) w2B[t]      = __float2bfloat16(ldf<BF>(w2ss, t));
    if (t < 64) w2B[64 + t] = __float2bfloat16(ldf<BF>(w2sv, t));
    if (t < 32) {
        w2B[128 + t] = __float2bfloat16(ldf<BF>(w2vs, t));
        w2B[160 + t] = __float2bfloat16(ldf<BF>(w2vv0, t));
        w2B[192 + t] = __float2bfloat16(ldf<BF>(w2vv1, t));
    }
}

// ---------------- Kernel 1: per-node layernorm + projections (4 nodes/block) ----------------
template<int BF>
__global__ __launch_bounds__(256) void k_node(
    const void* __restrict__ node, const void* __restrict__ gs,
    const void* __restrict__ bs, const void* __restrict__ gv,
    const void* __restrict__ Wss, const void* __restrict__ Wvs,
    const void* __restrict__ Wsd, const void* __restrict__ Wvd,
    bf16* __restrict__ ssrc, bf16* __restrict__ sdst,
    bf16* __restrict__ vsrc, bf16* __restrict__ vdst,
    const int* __restrict__ flags, int N)
{
    if (flags[0] != BF) return;
    int wv = threadIdx.x >> 6, lane = threadIdx.x & 63;
    int n = blockIdx.x * 4 + wv; if (n >= N) return;
    __shared__ float shs[4][64];
    __shared__ float shv[4][96];
    size_t nb = (size_t)n * 160;

    float s  = ldf<BF>(node, nb + lane);
    float mu = wave_sum64(s) * (1.f / 64.f);
    float d  = s - mu;
    float var = wave_sum64(d * d) * (1.f / 64.f);
    float sn  = d * rsqrtf(var + EPSN) * ldf<BF>(gs, lane) + ldf<BF>(bs, lane);
    shs[wv][lane] = sn;

    float v0 = 0.f, v1 = 0.f, v2 = 0.f, q = 0.f;
    if (lane < 32) {
        v0 = ldf<BF>(node, nb + 64 + lane * 3 + 0);
        v1 = ldf<BF>(node, nb + 64 + lane * 3 + 1);
        v2 = ldf<BF>(node, nb + 64 + lane * 3 + 2);
        q = v0 * v0 + v1 * v1 + v2 * v2;
    }
    float msq = wave_sum64(q) * (1.f / 32.f);
    float inv = rsqrtf(msq + EPSN);
    if (lane < 32) {
        float g = ldf<BF>(gv, lane);
        shv[wv][0 * 32 + lane] = v0 * inv * g;
        shv[wv][1 * 32 + lane] = v1 * inv * g;
        shv[wv][2 * 32 + lane] = v2 * inv * g;
    }
    // same-wave LDS write->read: in-order

    float a1 = 0.f, a2 = 0.f;
    for (int c = 0; c < 64; ++c) {
        float sc = shs[wv][c];
        a1 += sc * ldf<BF>(Wss, c * 64 + lane);
        a2 += sc * ldf<BF>(Wsd, c * 64 + lane);
    }
    ssrc[(size_t)n * 64 + lane] = __float2bfloat16(a1);
    sdst[(size_t)n * 64 + lane] = __float2bfloat16(a2);

    {
        int x = lane >> 5, dd = lane & 31;
        float p1 = 0.f, p2 = 0.f;
        for (int c = 0; c < 32; ++c) {
            float vc = shv[wv][x * 32 + c];
            p1 += vc * ldf<BF>(Wvs, c * 32 + dd);
            p2 += vc * ldf<BF>(Wvd, c * 32 + dd);
        }
        vsrc[(size_t)n * 96 + x * 32 + dd] = __float2bfloat16(p1);
        vdst[(size_t)n * 96 + x * 32 + dd] = __float2bfloat16(p2);
    }
    if (lane < 32) {
        int dd = lane;
        float p1 = 0.f, p2 = 0.f;
        for (int c = 0; c < 32; ++c) {
            float vc = shv[wv][2 * 32 + c];
            p1 += vc * ldf<BF>(Wvs, c * 32 + dd);
            p2 += vc * ldf<BF>(Wvd, c * 32 + dd);
        }
        vsrc[(size_t)n * 96 + 64 + dd] = __float2bfloat16(p1);
        vdst[(size_t)n * 96 + 64 + dd] = __float2bfloat16(p2);
    }
}

// ---------------- Phase 1 (chunked): gather + w1 + m1 TP -> global m1 [(e-ebase)][480] ----------------
template<int BF>
__global__ __launch_bounds__(256, 4) void k_m1(
    const void* __restrict__ eidx, const void* __restrict__ rbf, const void* __restrict__ rsh,
    const bf16* __restrict__ WrbfT,
    const bf16* __restrict__ ssrc, const bf16* __restrict__ sdst,
    const bf16* __restrict__ vsrc, const bf16* __restrict__ vdst,
    bf16* __restrict__ m1, const int* __restrict__ flags, int E,
    long long ebase, long long eend)
{
    if (flags[0] != BF) return;
    const int i64 = flags[1];

    __shared__ __align__(16) float sRbf[4][16][20];
    __shared__ __align__(16) float sY[4][16][4];
    __shared__ int sSD[4][32];

    int wv = threadIdx.x >> 6, l = threadIdx.x & 63;
    int q = l >> 4, m = l & 15;
    long long eb = ebase + ((long long)blockIdx.x * 4 + wv) * 16;
    if (eb >= eend) return;

    if (l < 32) {
        long long ee = eb + (l & 15); if (ee > eend - 1) ee = eend - 1;
        long long off = (l < 16) ? ee : ((long long)E + ee);
        sSD[wv][l] = i64 ? (int)((const long long*)eidx)[off] : ((const int*)eidx)[off];
    }
    {
        long long ee = eb + (l >> 2); if (ee > eend - 1) ee = eend - 1;
        sY[wv][l >> 2][l & 3] = ldf<BF>(rsh, (size_t)ee * 4 + (l & 3));
    }
    #pragma unroll
    for (int j = 0; j < 4; ++j) {
        long long ee = eb + j * 4 + q; if (ee > eend - 1) ee = eend - 1;
        sRbf[wv][m][j * 4 + q] = ldf<BF>(rbf, (size_t)ee * 16 + m);
    }

    const __bf16* wrt = (const __bf16*)WrbfT;
    int lv = l & 31;
    bfv8 w0a = *(const bfv8*)(wrt + l * 16);
    bfv8 w0b = *(const bfv8*)(wrt + l * 16 + 8);
    bfv8 w1a = *(const bfv8*)(wrt + (64 + l) * 16);
    bfv8 w1b = *(const bfv8*)(wrt + (64 + l) * 16 + 8);
    bfv8 w2a = *(const bfv8*)(wrt + (128 + lv) * 16);
    bfv8 w2b = *(const bfv8*)(wrt + (128 + lv) * 16 + 8);
    bfv8 w3a = *(const bfv8*)(wrt + (160 + lv) * 16);
    bfv8 w3b = *(const bfv8*)(wrt + (160 + lv) * 16 + 8);
    bfv8 w4a = *(const bfv8*)(wrt + (192 + lv) * 16);
    bfv8 w4b = *(const bfv8*)(wrt + (192 + lv) * 16 + 8);

    #pragma unroll 1
    for (int j = 0; j < 4; ++j) {
        int srcK[4], dstK[4];
        float y0k[4], yxk[4], yyk[4], yzk[4];
        float ms[4];
        float mv0[4] = {0,0,0,0}, mv1[4] = {0,0,0,0}, mv2[4] = {0,0,0,0};
        #pragma unroll
        for (int k = 0; k < 4; ++k) {
            srcK[k] = sSD[wv][4 * j + k];
            dstK[k] = sSD[wv][16 + 4 * j + k];
            float4 yy = *(const float4*)&sY[wv][4 * j + k][0];
            y0k[k] = yy.x; yxk[k] = yy.y; yyk[k] = yy.z; yzk[k] = yy.w;
            ms[k] = b2f(ssrc[(size_t)srcK[k] * 64 + l]) + b2f(sdst[(size_t)dstK[k] * 64 + l]);
        }
        if (l < 32) {
            #pragma unroll
            for (int k = 0; k < 4; ++k) {
                mv0[k] = b2f(vsrc[(size_t)srcK[k] * 96 +      l]) + b2f(vdst[(size_t)dstK[k] * 96 +      l]);
                mv1[k] = b2f(vsrc[(size_t)srcK[k] * 96 + 32 + l]) + b2f(vdst[(size_t)dstK[k] * 96 + 32 + l]);
                mv2[k] = b2f(vsrc[(size_t)srcK[k] * 96 + 64 + l]) + b2f(vdst[(size_t)dstK[k] * 96 + 64 + l]);
            }
        }
        float wss[4] = {0,0,0,0}, wsv[4] = {0,0,0,0};
        float wvs[4] = {0,0,0,0}, wv0[4] = {0,0,0,0}, wv1[4] = {0,0,0,0};
        #pragma unroll
        for (int b = 0; b < 16; ++b) {
            float2 ra = *(const float2*)&sRbf[wv][b][4 * j];
            float2 rb = *(const float2*)&sRbf[wv][b][4 * j + 2];
            float r0 = ra.x, r1 = ra.y, r2 = rb.x, r3 = rb.y;
            float wa  = (float)(b < 8 ? w0a[b] : w0b[b - 8]);
            float wb_ = (float)(b < 8 ? w1a[b] : w1b[b - 8]);
            float wc  = (float)(b < 8 ? w2a[b] : w2b[b - 8]);
            float wd  = (float)(b < 8 ? w3a[b] : w3b[b - 8]);
            float we  = (float)(b < 8 ? w4a[b] : w4b[b - 8]);
            wss[0] += r0 * wa;  wss[1] += r1 * wa;  wss[2] += r2 * wa;  wss[3] += r3 * wa;
            wsv[0] += r0 * wb_; wsv[1] += r1 * wb_; wsv[2] += r2 * wb_; wsv[3] += r3 * wb_;
            wvs[0] += r0 * wc;  wvs[1] += r1 * wc;  wvs[2] += r2 * wc;  wvs[3] += r3 * wc;
            wv0[0] += r0 * wd;  wv0[1] += r1 * wd;  wv0[2] += r2 * wd;  wv0[3] += r3 * wd;
            wv1[0] += r0 * we;  wv1[1] += r1 * we;  wv1[2] += r2 * we;  wv1[3] += r3 * we;
        }
        #pragma unroll
        for (int k = 0; k < 4; ++k) {
            long long ee = eb + 4 * j + k; if (ee > eend - 1) ee = eend - 1;
            bf16* row = m1 + (size_t)(ee - ebase) * 480;
            row[l] = __float2bfloat16(wss[k] * ms[k] * y0k[k]);
            float sv = wsv[k] * ms[k];
            row[96 +   0 + l] = __float2bfloat16(sv * yxk[k]);
            row[96 + 128 + l] = __float2bfloat16(sv * yyk[k]);
            row[96 + 256 + l] = __float2bfloat16(sv * yzk[k]);
            if (l < 32) {
                row[64 + l] = __float2bfloat16(
                    wv0[k] * (mv0[k] * yxk[k] + mv1[k] * yyk[k] + mv2[k] * yzk[k]) * SQRT3_INV);
                row[96 +   0 + 64 + l] = __float2bfloat16(wvs[k] * mv0[k] * y0k[k]);
                row[96 + 128 + 64 + l] = __float2bfloat16(wvs[k] * mv1[k] * y0k[k]);
                row[96 + 256 + 64 + l] = __float2bfloat16(wvs[k] * mv2[k] * y0k[k]);
                float cx = mv1[k] * yzk[k] - mv2[k] * yyk[k];
                float cy = mv2[k] * yxk[k] - mv0[k] * yzk[k];
                float cz = mv0[k] * yyk[k] - mv1[k] * yxk[k];
                row[96 +   0 + 96 + l] = __float2bfloat16(wv1[k] * cx * SQRT2_INV);
                row[96 + 128 + 96 + l] = __float2bfloat16(wv1[k] * cy * SQRT2_INV);
                row[96 + 256 + 96 + l] = __float2bfloat16(wv1[k] * cz * SQRT2_INV);
            }
        }
    }
}

// ---------------- Phase 2 (chunked): MFMA chains from global m1, plane-at-a-time m2, scatter ----------------
// Per-wave LDS: A2S [16][104] (m2_s), PB [16][136] (val_s staging then m2_v plane staging)
static constexpr int K2_AS = 0,    K2_SS = 104;
static constexpr int K2_PB = 1664, K2_SA = 72, K2_SV = 136;
static constexpr int K2_TOT = 3840;

template<int BF>
__global__ __launch_bounds__(256, 3) void k_edge2(
    const void* __restrict__ eidx, const void* __restrict__ rsh,
    const bf16* __restrict__ WalphaT, const bf16* __restrict__ WsvalT, const bf16* __restrict__ WsvlinT,
    const bf16* __restrict__ WvvalT, const bf16* __restrict__ WvvlinT, const bf16* __restrict__ WgT,
    const bf16* __restrict__ adotB, const bf16* __restrict__ w2B,
    const bf16* __restrict__ m1,
    float* __restrict__ den, float* __restrict__ agg,
    const int* __restrict__ flags, int E,
    long long ebase, long long eend)
{
    if (flags[0] != BF) return;
    const int i64 = flags[1];

    __shared__ __align__(16) __bf16 sA[4][K2_TOT];
    __shared__ __align__(16) float sY[4][16][4];
    __shared__ int sDst[4][16];

    int wv = threadIdx.x >> 6, l = threadIdx.x & 63;
    int q = l >> 4, m = l & 15;
    long long eb = ebase + ((long long)blockIdx.x * 4 + wv) * 16;
    if (eb >= eend) return;
    __bf16* H = &sA[wv][0];
    const int kq = q * 8;

    if (l < 16) {
        long long ee = eb + l; if (ee > eend - 1) ee = eend - 1;
        sDst[wv][l] = i64 ? (int)((const long long*)eidx)[(long long)E + ee]
                          : ((const int*)eidx)[(size_t)E + ee];
    }
    {
        long long ee = eb + (l >> 2); if (ee > eend - 1) ee = eend - 1;
        sY[wv][l >> 2][l & 3] = ldf<BF>(rsh, (size_t)ee * 4 + (l & 3));
    }

    long long erow = eb + m; if (erow > eend - 1) erow = eend - 1;
    const __bf16* mrow = (const __bf16*)m1 + (size_t)(erow - ebase) * 480;

    bfv8 a1s0 = *(const bfv8*)(mrow + 0  + kq);
    bfv8 a1s1 = *(const bfv8*)(mrow + 32 + kq);
    bfv8 a1s2 = *(const bfv8*)(mrow + 64 + kq);

    // ---- S2: val_s = m1_s @ Ws_val; PRE-sigmoid -> PB, sigmoid -> regs ----
    f4 vals[4];
    #pragma unroll
    for (int nt = 0; nt < 4; ++nt) {
        const __bf16* bp = (const __bf16*)WsvalT + (size_t)(nt * 16 + m) * 96 + kq;
        f4 acc = {0.f, 0.f, 0.f, 0.f};
        acc = mf(a1s0, *(const bfv8*)(bp),      acc);
        acc = mf(a1s1, *(const bfv8*)(bp + 32), acc);
        acc = mf(a1s2, *(const bfv8*)(bp + 64), acc);
        vals[nt] = acc;
    }
    #pragma unroll
    for (int nt = 0; nt < 4; ++nt)
        #pragma unroll
        for (int r = 0; r < 4; ++r) {
            float v = vals[nt][r];
            H[K2_PB + (q * 4 + r) * K2_SA + nt * 16 + m] = (__bf16)v;   // PRE-sigmoid
            vals[nt][r] = 1.f / (1.f + __expf(-v));
        }

    // ---- S3: gate = sigmoid(val_s_pre @ Wg) ----
    bfv8 av0 = *(const bfv8*)(H + K2_PB + m * K2_SA + 0  + kq);
    bfv8 av1 = *(const bfv8*)(H + K2_PB + m * K2_SA + 32 + kq);
    f4 gate[2];
    #pragma unroll
    for (int nt = 0; nt < 2; ++nt) {
        const __bf16* bp = (const __bf16*)WgT + (size_t)(nt * 16 + m) * 64 + kq;
        f4 acc = {0.f, 0.f, 0.f, 0.f};
        acc = mf(av0, *(const bfv8*)(bp),      acc);
        acc = mf(av1, *(const bfv8*)(bp + 32), acc);
        gate[nt] = acc;
    }
    #pragma unroll
    for (int nt = 0; nt < 2; ++nt)
        #pragma unroll
        for (int r = 0; r < 4; ++r)
            gate[nt][r] = 1.f / (1.f + __expf(-gate[nt][r]));

    // ---- S4: attention logits + ex ----
    float ex_[4][4];
    #pragma unroll
    for (int nt = 0; nt < 4; ++nt) {
        const __bf16* bp = (const __bf16*)WalphaT + (size_t)(nt * 16 + m) * 96 + kq;
        f4 acc = {0.f, 0.f, 0.f, 0.f};
        acc = mf(a1s0, *(const bfv8*)(bp),      acc);
        acc = mf(a1s1, *(const bfv8*)(bp + 32), acc);
        acc = mf(a1s2, *(const bfv8*)(bp + 64), acc);
        float ad = b2f(adotB[nt * 16 + m]);
        #pragma unroll
        for (int r = 0; r < 4; ++r) {
            float tv = acc[r];
            tv = tv > 0.f ? tv : 0.2f * tv;
            tv *= ad;
            tv += __shfl_xor(tv, 1); tv += __shfl_xor(tv, 2);
            tv += __shfl_xor(tv, 4); tv += __shfl_xor(tv, 8);
            tv = fminf(fmaxf(tv, -60.f), 60.f);
            ex_[nt][r] = __expf(tv);
        }
    }

    // ---- S5: val_v = (m1_v @ Wv_val) * gate, plane fragments from global ----
    f4 vv[3][2];
    #pragma unroll
    for (int x = 0; x < 3; ++x) {
        vv[x][0] = (f4){0.f, 0.f, 0.f, 0.f};
        vv[x][1] = (f4){0.f, 0.f, 0.f, 0.f};
        const __bf16* pr = mrow + 96 + x * 128;
        #pragma unroll
        for (int kt = 0; kt < 4; ++kt) {
            bfv8 a = *(const bfv8*)(pr + kt * 32 + kq);
            const __bf16* bp0 = (const __bf16*)WvvalT + (size_t)(0 * 16 + m) * 128 + kt * 32 + kq;
            const __bf16* bp1 = (const __bf16*)WvvalT + (size_t)(1 * 16 + m) * 128 + kt * 32 + kq;
            vv[x][0] = mf(a, *(const bfv8*)bp0, vv[x][0]);
            vv[x][1] = mf(a, *(const bfv8*)bp1, vv[x][1]);
        }
    }
    #pragma unroll
    for (int x = 0; x < 3; ++x)
        #pragma unroll
        for (int nt = 0; nt < 2; ++nt)
            #pragma unroll
            for (int r = 0; r < 4; ++r)
                vv[x][nt][r] *= gate[nt][r];

    // ---- S6a: m2_s -> A2S ----
    float c2ss[4], c2sv[4];
    #pragma unroll
    for (int nt = 0; nt < 4; ++nt) {
        c2ss[nt] = b2f(w2B[nt * 16 + m]);
        c2sv[nt] = b2f(w2B[64 + nt * 16 + m]);
    }
    float c2vs[2], c2v0[2], c2v1[2];
    #pragma unroll
    for (int nt = 0; nt < 2; ++nt) {
        c2vs[nt] = b2f(w2B[128 + nt * 16 + m]);
        c2v0[nt] = b2f(w2B[160 + nt * 16 + m]);
        c2v1[nt] = b2f(w2B[192 + nt * 16 + m]);
    }
    #pragma unroll
    for (int r = 0; r < 4; ++r) {
        int e = q * 4 + r;
        float4 yy = *(const float4*)&sY[wv][e][0];
        float y0 = yy.x, yx = yy.y, yh = yy.z, yz = yy.w;
        int rS = K2_AS + e * K2_SS;
        #pragma unroll
        for (int nt = 0; nt < 4; ++nt)
            H[rS + nt * 16 + m] = (__bf16)(c2ss[nt] * vals[nt][r] * y0);
        #pragma unroll
        for (int nt = 0; nt < 2; ++nt) {
            float v0 = vv[0][nt][r], v1 = vv[1][nt][r], v2 = vv[2][nt][r];
            H[rS + 64 + nt * 16 + m] = (__bf16)(c2v0[nt] * (v0 * yx + v1 * yh + v2 * yz) * SQRT3_INV);
        }
    }

    // ---- S7a: hs = m2_s @ Ws_vlin ----
    bfv8 a2s0 = *(const bfv8*)(H + K2_AS + m * K2_SS + 0  + kq);
    bfv8 a2s1 = *(const bfv8*)(H + K2_AS + m * K2_SS + 32 + kq);
    bfv8 a2s2 = *(const bfv8*)(H + K2_AS + m * K2_SS + 64 + kq);
    f4 hs[4];
    #pragma unroll
    for (int nt = 0; nt < 4; ++nt) {
        const __bf16* bp = (const __bf16*)WsvlinT + (size_t)(nt * 16 + m) * 96 + kq;
        f4 acc = {0.f, 0.f, 0.f, 0.f};
        acc = mf(a2s0, *(const bfv8*)(bp),      acc);
        acc = mf(a2s1, *(const bfv8*)(bp + 32), acc);
        acc = mf(a2s2, *(const bfv8*)(bp + 64), acc);
        hs[nt] = acc;
    }

    // ---- S6b/S7b: m2_v plane-at-a-time through PB -> hv ----
    f4 hv[3][2];
    #pragma unroll 1
    for (int x = 0; x < 3; ++x) {
        #pragma unroll
        for (int r = 0; r < 4; ++r) {
            int e = q * 4 + r;
            float4 yy = *(const float4*)&sY[wv][e][0];
            float y0 = yy.x;
            float y1c = (x == 0) ? yy.y : (x == 1) ? yy.z : yy.w;
            int rV = K2_PB + e * K2_SV;
            #pragma unroll
            for (int nt = 0; nt < 4; ++nt)
                H[rV + nt * 16 + m] = (__bf16)(c2sv[nt] * vals[nt][r] * y1c);
            float ya = yy.y, yb = yy.z, yc = yy.w;
            #pragma unroll
            for (int nt = 0; nt < 2; ++nt) {
                float v0 = vv[0][nt][r], v1 = vv[1][nt][r], v2 = vv[2][nt][r];
                H[rV + 64 + nt * 16 + m] = (__bf16)(c2vs[nt] * ((x==0)?v0:(x==1)?v1:v2) * y0);
                float cr = (x == 0) ? (v1 * yc - v2 * yb)
                         : (x == 1) ? (v2 * ya - v0 * yc)
                                    : (v0 * yb - v1 * ya);
                H[rV + 96 + nt * 16 + m] = (__bf16)(c2v1[nt] * cr * SQRT2_INV);
            }
        }
        f4 h0 = {0.f, 0.f, 0.f, 0.f}, h1 = {0.f, 0.f, 0.f, 0.f};
        #pragma unroll
        for (int kt = 0; kt < 4; ++kt) {
            bfv8 a = *(const bfv8*)(H + K2_PB + m * K2_SV + kt * 32 + kq);
            const __bf16* bp0 = (const __bf16*)WvvlinT + (size_t)(0 * 16 + m) * 128 + kt * 32 + kq;
            const __bf16* bp1 = (const __bf16*)WvvlinT + (size_t)(1 * 16 + m) * 128 + kt * 32 + kq;
            h0 = mf(a, *(const bfv8*)bp0, h0);
            h1 = mf(a, *(const bfv8*)bp1, h1);
        }
        hv[x][0] = h0; hv[x][1] = h1;
    }

    // ---- S8: scatter ----
    #pragma unroll
    for (int r = 0; r < 4; ++r) {
        int e = q * 4 + r;
        long long eg = eb + e;
        if (eg < eend) {
            int d = sDst[wv][e];
            float* rowp = agg + (size_t)d * 160;
            if (m < 4) {
                float exm = (m == 0) ? ex_[0][r] : (m == 1) ? ex_[1][r] : (m == 2) ? ex_[2][r] : ex_[3][r];
                unsafeAtomicAdd(den + (size_t)d * 4 + m, exm);
            }
            #pragma unroll
            for (int nt = 0; nt < 4; ++nt)
                unsafeAtomicAdd(rowp + nt * 40 + m, ex_[nt][r] * hs[nt][r]);
            #pragma unroll
            for (int nt = 0; nt < 2; ++nt) {
                int c = nt * 16 + m;
                int hh = c >> 3, dd = c & 7;
                float exv = (m >= 8) ? ex_[2 * nt + 1][r] : ex_[2 * nt][r];
                float* vb = rowp + hh * 40 + 16 + dd * 3;
                unsafeAtomicAdd(vb + 0, exv * hv[0][nt][r]);
                unsafeAtomicAdd(vb + 1, exv * hv[1][nt][r]);
                unsafeAtomicAdd(vb + 2, exv * hv[2][nt][r]);
            }
        }
    }
}

// ---------------- Fallback fused edge kernel (verified R4 path) ----------------
static constexpr int A1S = 0,    SS = 104;
static constexpr int A1V = 1664, PV = 2176, SV = 136;
static constexpr int VAL = 8192, SA = 72;
static constexpr int HSZ = 9344;

template<int BF>
__global__ __launch_bounds__(256, 2) void k_edge_fused(
    const void* __restrict__ eidx, const void* __restrict__ rbf, const void* __restrict__ rsh,
    const bf16* __restrict__ WalphaT, const bf16* __restrict__ WsvalT, const bf16* __restrict__ WsvlinT,
    const bf16* __restrict__ WvvalT, const bf16* __restrict__ WvvlinT, const bf16* __restrict__ WgT,
    const bf16* __restrict__ WrbfT, const bf16* __restrict__ adotB, const bf16* __restrict__ w2B,
    const bf16* __restrict__ ssrc, const bf16* __restrict__ sdst,
    const bf16* __restrict__ vsrc, const bf16* __restrict__ vdst,
    float* __restrict__ den, float* __restrict__ agg,
    const int* __restrict__ flags, int E)
{
    if (flags[0] != BF) return;
    const int i64 = flags[1];

    __shared__ __align__(16) __bf16 sH[4][HSZ];
    __shared__ __align__(16) float sRbf[4][16][20];
    __shared__ __align__(16) float sY[4][16][4];
    __shared__ int sSD[4][32];

    int wv = threadIdx.x >> 6, l = threadIdx.x & 63;
    int q = l >> 4, m = l & 15;
    long long eb = ((long long)blockIdx.x * 4 + wv) * 16;
    if (eb >= E) return;
    __bf16* H = &sH[wv][0];

    if (l < 32) {
        long long ee = eb + (l & 15); if (ee > (long long)E - 1) ee = E - 1;
        long long off = (l < 16) ? ee : ((long long)E + ee);
        sSD[wv][l] = i64 ? (int)((const long long*)eidx)[off] : ((const int*)eidx)[off];
    }
    {
        long long ee = eb + (l >> 2); if (ee > (long long)E - 1) ee = E - 1;
        sY[wv][l >> 2][l & 3] = ldf<BF>(rsh, (size_t)ee * 4 + (l & 3));
    }
    #pragma unroll
    for (int j = 0; j < 4; ++j) {
        long long ee = eb + j * 4 + q; if (ee > (long long)E - 1) ee = E - 1;
        sRbf[wv][m][j * 4 + q] = ldf<BF>(rbf, (size_t)ee * 16 + m);
    }

    const __bf16* wrt = (const __bf16*)WrbfT;
    int lv = l & 31;
    bfv8 w0a = *(const bfv8*)(wrt + l * 16);
    bfv8 w0b = *(const bfv8*)(wrt + l * 16 + 8);
    bfv8 w1a = *(const bfv8*)(wrt + (64 + l) * 16);
    bfv8 w1b = *(const bfv8*)(wrt + (64 + l) * 16 + 8);
    bfv8 w2a = *(const bfv8*)(wrt + (128 + lv) * 16);
    bfv8 w2b = *(const bfv8*)(wrt + (128 + lv) * 16 + 8);
    bfv8 w3a = *(const bfv8*)(wrt + (160 + lv) * 16);
    bfv8 w3b = *(const bfv8*)(wrt + (160 + lv) * 16 + 8);
    bfv8 w4a = *(const bfv8*)(wrt + (192 + lv) * 16);
    bfv8 w4b = *(const bfv8*)(wrt + (192 + lv) * 16 + 8);

    #pragma unroll 1
    for (int j = 0; j < 4; ++j) {
        int srcK[4], dstK[4];
        float y0k[4], yxk[4], yyk[4], yzk[4];
        float ms[4];
        float mv0[4] = {0,0,0,0}, mv1[4] = {0,0,0,0}, mv2[4] = {0,0,0,0};
        #pragma unroll
        for (int k = 0; k < 4; ++k) {
            srcK[k] = sSD[wv][4 * j + k];
            dstK[k] = sSD[wv][16 + 4 * j + k];
            float4 yy = *(const float4*)&sY[wv][4 * j + k][0];
            y0k[k] = yy.x; yxk[k] = yy.y; yyk[k] = yy.z; yzk[k] = yy.w;
            ms[k] = b2f(ssrc[(size_t)srcK[k] * 64 + l]) + b2f(sdst[(size_t)dstK[k] * 64 + l]);
        }
        if (l < 32) {
            #pragma unroll
            for (int k = 0; k < 4; ++k) {
                mv0[k] = b2f(vsrc[(size_t)srcK[k] * 96 +      l]) + b2f(vdst[(size_t)dstK[k] * 96 +      l]);
                mv1[k] = b2f(vsrc[(size_t)srcK[k] * 96 + 32 + l]) + b2f(vdst[(size_t)dstK[k] * 96 + 32 + l]);
                mv2[k] = b2f(vsrc[(size_t)srcK[k] * 96 + 64 + l]) + b2f(vdst[(size_t)dstK[k] * 96 + 64 + l]);
            }
        }
        float wss[4] = {0,0,0,0}, wsv[4] = {0,0,0,0};
        float wvs[4] = {0,0,0,0}, wv0[4] = {0,0,0,0}, wv1[4] = {0,0,0,0};
        #pragma unroll
        for (int b = 0; b < 16; ++b) {
            float2 ra = *(const float2*)&sRbf[wv][b][4 * j];
            float2 rb = *(const float2*)&sRbf[wv][b][4 * j + 2];
            float r0 = ra.x, r1 = ra.y, r2 = rb.x, r3 = rb.y;
            float wa  = (float)(b < 8 ? w0a[b] : w0b[b - 8]);
            float wb_ = (float)(b < 8 ? w1a[b] : w1b[b - 8]);
            float wc  = (float)(b < 8 ? w2a[b] : w2b[b - 8]);
            float wd  = (float)(b < 8 ? w3a[b] : w3b[b - 8]);
            float we  = (float)(b < 8 ? w4a[b] : w4b[b - 8]);
            wss[0] += r0 * wa;  wss[1] += r1 * wa;  wss[2] += r2 * wa;  wss[3] += r3 * wa;
            wsv[0] += r0 * wb_; wsv[1] += r1 * wb_; wsv[2] += r2 * wb_; wsv[3] += r3 * wb_;
            wvs[0] += r0 * wc;  wvs[1] += r1 * wc;  wvs[2] += r2 * wc;  wvs[3] += r3 * wc;
            wv0[0] += r0 * wd;  wv0[1] += r1 * wd;  wv0[2] += r2 * wd;  wv0[3] += r3 * wd;
            wv1[0] += r0 * we;  wv1[1] += r1 * we;  wv1[2] += r2 * we;  wv1[3] += r3 * we;
        }
        #pragma unroll
        for (int k = 0; k < 4; ++k) {
            int e = 4 * j + k;
            H[A1S + e * SS + l] = (__bf16)(wss[k] * ms[k] * y0k[k]);
            float sv = wsv[k] * ms[k];
            H[A1V + 0 * PV + e * SV + l] = (__bf16)(sv * yxk[k]);
            H[A1V + 1 * PV + e * SV + l] = (__bf16)(sv * yyk[k]);
            H[A1V + 2 * PV + e * SV + l] = (__bf16)(sv * yzk[k]);
        }
        if (l < 32) {
            #pragma unroll
            for (int k = 0; k < 4; ++k) {
                int e = 4 * j + k;
                H[A1S + e * SS + 64 + l] =
                    (__bf16)(wv0[k] * (mv0[k] * yxk[k] + mv1[k] * yyk[k] + mv2[k] * yzk[k]) * SQRT3_INV);
                H[A1V + 0 * PV + e * SV + 64 + l] = (__bf16)(wvs[k] * mv0[k] * y0k[k]);
                H[A1V + 1 * PV + e * SV + 64 + l] = (__bf16)(wvs[k] * mv1[k] * y0k[k]);
                H[A1V + 2 * PV + e * SV + 64 + l] = (__bf16)(wvs[k] * mv2[k] * y0k[k]);
                float cx = mv1[k] * yzk[k] - mv2[k] * yyk[k];
                float cy = mv2[k] * yxk[k] - mv0[k] * yzk[k];
                float cz = mv0[k] * yyk[k] - mv1[k] * yxk[k];
                H[A1V + 0 * PV + e * SV + 96 + l] = (__bf16)(wv1[k] * cx * SQRT2_INV);
                H[A1V + 1 * PV + e * SV + 96 + l] = (__bf16)(wv1[k] * cy * SQRT2_INV);
                H[A1V + 2 * PV + e * SV + 96 + l] = (__bf16)(wv1[k] * cz * SQRT2_INV);
            }
        }
    }

    const int kq = q * 8;

    bfv8 a1s0 = *(const bfv8*)(H + A1S + m * SS + 0  + kq);
    bfv8 a1s1 = *(const bfv8*)(H + A1S + m * SS + 32 + kq);
    bfv8 a1s2 = *(const bfv8*)(H + A1S + m * SS + 64 + kq);
    f4 vals[4];
    #pragma unroll
    for (int nt = 0; nt < 4; ++nt) {
        const __bf16* bp = (const __bf16*)WsvalT + (size_t)(nt * 16 + m) * 96 + kq;
        f4 acc = {0.f, 0.f, 0.f, 0.f};
        acc = mf(a1s0, *(const bfv8*)(bp),      acc);
        acc = mf(a1s1, *(const bfv8*)(bp + 32), acc);
        acc = mf(a1s2, *(const bfv8*)(bp + 64), acc);
        vals[nt] = acc;
    }
    #pragma unroll
    for (int nt = 0; nt < 4; ++nt)
        #pragma unroll
        for (int r = 0; r < 4; ++r) {
            float v = vals[nt][r];
            H[VAL + (q * 4 + r) * SA + nt * 16 + m] = (__bf16)v;
            vals[nt][r] = 1.f / (1.f + __expf(-v));
        }

    bfv8 av0 = *(const bfv8*)(H + VAL + m * SA + 0  + kq);
    bfv8 av1 = *(const bfv8*)(H + VAL + m * SA + 32 + kq);
    f4 gate[2];
    #pragma unroll
    for (int nt = 0; nt < 2; ++nt) {
        const __bf16* bp = (const __bf16*)WgT + (size_t)(nt * 16 + m) * 64 + kq;
        f4 acc = {0.f, 0.f, 0.f, 0.f};
        acc = mf(av0, *(const bfv8*)(bp),      acc);
        acc = mf(av1, *(const bfv8*)(bp + 32), acc);
        gate[nt] = acc;
    }
    #pragma unroll
    for (int nt = 0; nt < 2; ++nt)
        #pragma unroll
        for (int r = 0; r < 4; ++r)
            gate[nt][r] = 1.f / (1.f + __expf(-gate[nt][r]));

    float ex_[4][4];
    #pragma unroll
    for (int nt = 0; nt < 4; ++nt) {
        const __bf16* bp = (const __bf16*)WalphaT + (size_t)(nt * 16 + m) * 96 + kq;
        f4 acc = {0.f, 0.f, 0.f, 0.f};
        acc = mf(a1s0, *(const bfv8*)(bp),      acc);
        acc = mf(a1s1, *(const bfv8*)(bp + 32), acc);
        acc = mf(a1s2, *(const bfv8*)(bp + 64), acc);
        float ad = b2f(adotB[nt * 16 + m]);
        #pragma unroll
        for (int r = 0; r < 4; ++r) {
            float tv = acc[r];
            tv = tv > 0.f ? tv : 0.2f * tv;
            tv *= ad;
            tv += __shfl_xor(tv, 1); tv += __shfl_xor(tv, 2);
            tv += __shfl_xor(tv, 4); tv += __shfl_xor(tv, 8);
            tv = fminf(fmaxf(tv, -60.f), 60.f);
            ex_[nt][r] = __expf(tv);
        }
    }

    bfv8 a1v[3][4];
    #pragma unroll
    for (int x = 0; x < 3; ++x)
        #pragma unroll
        for (int kt = 0; kt < 4; ++kt)
            a1v[x][kt] = *(const bfv8*)(H + A1V + x * PV + m * SV + kt * 32 + kq);
    f4 vv[3][2];
    #pragma unroll
    for (int x = 0; x < 3; ++x)
        #pragma unroll
        for (int nt = 0; nt < 2; ++nt)
            vv[x][nt] = (f4){0.f, 0.f, 0.f, 0.f};
    #pragma unroll
    for (int nt = 0; nt < 2; ++nt) {
        const __bf16* bp = (const __bf16*)WvvalT + (size_t)(nt * 16 + m) * 128 + kq;
        #pragma unroll
        for (int kt = 0; kt < 4; ++kt) {
            bfv8 b = *(const bfv8*)(bp + kt * 32);
            vv[0][nt] = mf(a1v[0][kt], b, vv[0][nt]);
            vv[1][nt] = mf(a1v[1][kt], b, vv[1][nt]);
            vv[2][nt] = mf(a1v[2][kt], b, vv[2][nt]);
        }
    }
    #pragma unroll
    for (int x = 0; x < 3; ++x)
        #pragma unroll
        for (int nt = 0; nt < 2; ++nt)
            #pragma unroll
            for (int r = 0; r < 4; ++r)
                vv[x][nt][r] *= gate[nt][r];

    float c2ss[4], c2sv[4];
    #pragma unroll
    for (int nt = 0; nt < 4; ++nt) {
        c2ss[nt] = b2f(w2B[nt * 16 + m]);
        c2sv[nt] = b2f(w2B[64 + nt * 16 + m]);
    }
    float c2vs[2], c2v0[2], c2v1[2];
    #pragma unroll
    for (int nt = 0; nt < 2; ++nt) {
        c2vs[nt] = b2f(w2B[128 + nt * 16 + m]);
        c2v0[nt] = b2f(w2B[160 + nt * 16 + m]);
        c2v1[nt] = b2f(w2B[192 + nt * 16 + m]);
    }
    #pragma unroll
    for (int r = 0; r < 4; ++r) {
        int e = q * 4 + r;
        float4 yy = *(const float4*)&sY[wv][e][0];
        float y0 = yy.x, yx = yy.y, yh = yy.z, yz = yy.w;
        int rS  = A1S + e * SS;
        int rV0 = A1V + 0 * PV + e * SV;
        int rV1 = A1V + 1 * PV + e * SV;
        int rV2 = A1V + 2 * PV + e * SV;
        #pragma unroll
        for (int nt = 0; nt < 4; ++nt) {
            int c = nt * 16 + m;
            float va = vals[nt][r];
            H[rS + c] = (__bf16)(c2ss[nt] * va * y0);
            float t2 = c2sv[nt] * va;
            H[rV0 + c] = (__bf16)(t2 * yx);
            H[rV1 + c] = (__bf16)(t2 * yh);
            H[rV2 + c] = (__bf16)(t2 * yz);
        }
        #pragma unroll
        for (int nt = 0; nt < 2; ++nt) {
            int c = nt * 16 + m;
            float v0 = vv[0][nt][r], v1 = vv[1][nt][r], v2 = vv[2][nt][r];
            H[rS + 64 + c] = (__bf16)(c2v0[nt] * (v0 * yx + v1 * yh + v2 * yz) * SQRT3_INV);
            H[rV0 + 64 + c] = (__bf16)(c2vs[nt] * v0 * y0);
            H[rV1 + 64 + c] = (__bf16)(c2vs[nt] * v1 * y0);
            H[rV2 + 64 + c] = (__bf16)(c2vs[nt] * v2 * y0);
            float cx = v1 * yz - v2 * yh;
            float cy = v2 * yx - v0 * yz;
            float cz = v0 * yh - v1 * yx;
            H[rV0 + 96 + c] = (__bf16)(c2v1[nt] * cx * SQRT2_INV);
            H[rV1 + 96 + c] = (__bf16)(c2v1[nt] * cy * SQRT2_INV);
            H[rV2 + 96 + c] = (__bf16)(c2v1[nt] * cz * SQRT2_INV);
        }
    }

    bfv8 a2s0 = *(const bfv8*)(H + A1S + m * SS + 0  + kq);
    bfv8 a2s1 = *(const bfv8*)(H + A1S + m * SS + 32 + kq);
    bfv8 a2s2 = *(const bfv8*)(H + A1S + m * SS + 64 + kq);
    f4 hs[4];
    #pragma unroll
    for (int nt = 0; nt < 4; ++nt) {
        const __bf16* bp = (const __bf16*)WsvlinT + (size_t)(nt * 16 + m) * 96 + kq;
        f4 acc = {0.f, 0.f, 0.f, 0.f};
        acc = mf(a2s0, *(const bfv8*)(bp),      acc);
        acc = mf(a2s1, *(const bfv8*)(bp + 32), acc);
        acc = mf(a2s2, *(const bfv8*)(bp + 64), acc);
        hs[nt] = acc;
    }
    bfv8 a2v[3][4];
    #pragma unroll
    for (int x = 0; x < 3; ++x)
        #pragma unroll
        for (int kt = 0; kt < 4; ++kt)
            a2v[x][kt] = *(const bfv8*)(H + A1V + x * PV + m * SV + kt * 32 + kq);
    f4 hv[3][2];
    #pragma unroll
    for (int x = 0; x < 3; ++x)
        #pragma unroll
        for (int nt = 0; nt < 2; ++nt)
            hv[x][nt] = (f4){0.f, 0.f, 0.f, 0.f};
    #pragma unroll
    for (int nt = 0; nt < 2; ++nt) {
        const __bf16* bp = (const __bf16*)WvvlinT + (size_t)(nt * 16 + m) * 128 + kq;
        #pragma unroll
        for (int kt = 0; kt < 4; ++kt) {
            bfv8 b = *(const bfv8*)(bp + kt * 32);
            hv[0][nt] = mf(a2v[0][kt], b, hv[0][nt]);
            hv[1][nt] = mf(a2v[1][kt], b, hv[1][nt]);
            hv[2][nt] = mf(a2v[2][kt], b, hv[2][nt]);
        }
    }

    #pragma unroll
    for (int r = 0; r < 4; ++r) {
        int e = q * 4 + r;
        long long eg = eb + e;
        if (eg < E) {
            int d = sSD[wv][16 + e];
            float* rowp = agg + (size_t)d * 160;
            if (m < 4) {
                float exm = (m == 0) ? ex_[0][r] : (m == 1) ? ex_[1][r] : (m == 2) ? ex_[2][r] : ex_[3][r];
                unsafeAtomicAdd(den + (size_t)d * 4 + m, exm);
            }
            #pragma unroll
            for (int nt = 0; nt < 4; ++nt)
                unsafeAtomicAdd(rowp + nt * 40 + m, ex_[nt][r] * hs[nt][r]);
            #pragma unroll
            for (int nt = 0; nt < 2; ++nt) {
                int c = nt * 16 + m;
                int hh = c >> 3, dd = c & 7;
                float exv = (m >= 8) ? ex_[2 * nt + 1][r] : ex_[2 * nt][r];
                float* vb = rowp + hh * 40 + 16 + dd * 3;
                unsafeAtomicAdd(vb + 0, exv * hv[0][nt][r]);
                unsafeAtomicAdd(vb + 1, exv * hv[1][nt][r]);
                unsafeAtomicAdd(vb + 2, exv * hv[2][nt][r]);
            }
        }
    }
}

// ---------------- Kernel 3: normalize + output projection + residual (4 nodes/block) ----------------
template<int BF>
__global__ __launch_bounds__(256) void k_out(
    const void* __restrict__ node, const float* __restrict__ den,
    const float* __restrict__ agg, const void* __restrict__ Wps,
    const void* __restrict__ Wpv, void* __restrict__ out,
    const int* __restrict__ flags, int N)
{
    if (flags[0] != BF) return;
    int wv = threadIdx.x >> 6, lane = threadIdx.x & 63;
    int n = blockIdx.x * 4 + wv; if (n >= N) return;
    __shared__ float shs[4][64];
    __shared__ float shv[4][96];
    __shared__ float sinv[4][4];
    if (lane < 4) sinv[wv][lane] = 1.f / (den[(size_t)n * 4 + lane] + 1e-16f);
    for (int idx = lane; idx < 160; idx += 64) {
        int h = idx / 40, r = idx - h * 40;
        float val = agg[(size_t)n * 160 + idx] * sinv[wv][h];
        if (r < 16) shs[wv][h * 16 + r] = val;
        else { int rr = r - 16; int dd = rr / 3, x = rr - dd * 3; shv[wv][x * 32 + h * 8 + dd] = val; }
    }

    float acc = ldf<BF>(node, (size_t)n * 160 + lane);
    for (int c = 0; c < 64; ++c) acc += shs[wv][c] * ldf<BF>(Wps, c * 64 + lane);
    stf<BF>(out, (size_t)n * 160 + lane, acc);

    {
        int idx = lane; int dd = idx / 3, x = idx - dd * 3;
        float a = ldf<BF>(node, (size_t)n * 160 + 64 + idx);
        for (int c = 0; c < 32; ++c) a += shv[wv][x * 32 + c] * ldf<BF>(Wpv, c * 32 + dd);
        stf<BF>(out, (size_t)n * 160 + 64 + idx, a);
    }
    if (lane < 32) {
        int idx = 64 + lane; int dd = idx / 3, x = idx - dd * 3;
        float a = ldf<BF>(node, (size_t)n * 160 + 64 + idx);
        for (int c = 0; c < 32; ++c) a += shv[wv][x * 32 + c] * ldf<BF>(Wpv, c * 32 + dd);
        stf<BF>(out, (size_t)n * 160 + 64 + idx, a);
    }
}

// ---------------- Launch ----------------
extern "C" void kernel_launch(void* const* d_in, const int* in_sizes, int n_in,
                              void* d_out, int out_size, void* d_ws, size_t ws_size,
                              hipStream_t stream)
{
    const void* node   = d_in[0];
    const void* eidx   = d_in[1];
    const void* rbf    = d_in[2];
    const void* rsh    = d_in[3];
    const void* gs     = d_in[4];
    const void* bs     = d_in[5];
    const void* gv     = d_in[6];
    const void* Wss    = d_in[7];
    const void* Wvs    = d_in[8];
    const void* Wsd    = d_in[9];
    const void* Wvd    = d_in[10];
    const void* Wrbf   = d_in[11];
    const void* Walpha = d_in[12];
    const void* adot   = d_in[13];
    const void* Wsval  = d_in[14];
    const void* Wvval  = d_in[15];
    const void* Wg     = d_in[16];
    const void* w2ss   = d_in[17];
    const void* w2sv   = d_in[18];
    const void* w2vs   = d_in[19];
    const void* w2vv0  = d_in[20];
    const void* w2vv1  = d_in[21];
    const void* Wsvlin = d_in[22];
    const void* Wvvlin = d_in[23];
    const void* Wps    = d_in[24];
    const void* Wpv    = d_in[25];

    int N = in_sizes[0] / 160;
    int E = in_sizes[1] / 2;

    char* base = (char*)d_ws;
    int*  flags   = (int*)base;                  // 16 B
    bf16* WalphaT = (bf16*)(base + 16);
    bf16* WsvalT  = WalphaT + 6144;
    bf16* WsvlinT = WsvalT  + 6144;
    bf16* WvvalT  = WsvlinT + 6144;
    bf16* WvvlinT = WvvalT  + 4096;
    bf16* WgT     = WvvlinT + 4096;
    bf16* WrbfT   = WgT     + 2048;
    bf16* adotB   = WrbfT   + 3584;
    bf16* w2B     = adotB   + 64;
    bf16* ssrc    = w2B     + 224;
    bf16* sdst    = ssrc + (size_t)N * 64;
    bf16* vsrc    = sdst + (size_t)N * 64;
    bf16* vdst    = vsrc + (size_t)N * 96;
    float* den    = (float*)(vdst + (size_t)N * 96);
    float* agg    = den + (size_t)N * 4;
    bf16* m1buf   = (bf16*)(agg + (size_t)N * 160);

    size_t base_need = (size_t)((char*)m1buf - base);
    size_t avail = (ws_size > base_need) ? (ws_size - base_need) : 0;
    long long chunk = (long long)(avail / (480 * sizeof(bf16)));
    chunk = (chunk / 64) * 64;                        // block-unit aligned
    int nchunks = 0;
    if (chunk >= 64) nchunks = (int)(((long long)E + chunk - 1) / chunk);
    bool fast = (nchunks >= 1 && nchunks <= 12);

    k_sniff<<<1, 256, 0, stream>>>(node, eidx, flags);
    int zn = N * 164;
    k_zero<<<(zn + 255) / 256, 256, 0, stream>>>(den, zn);

    k_prep<1><<<16, 256, 0, stream>>>(Walpha, Wsval, Wsvlin, Wvval, Wvvlin, Wg, Wrbf, adot,
                                      w2ss, w2sv, w2vs, w2vv0, w2vv1,
                                      WalphaT, WsvalT, WsvlinT, WvvalT, WvvlinT, WgT, WrbfT,
                                      adotB, w2B, flags);
    k_prep<0><<<16, 256, 0, stream>>>(Walpha, Wsval, Wsvlin, Wvval, Wvvlin, Wg, Wrbf, adot,
                                      w2ss, w2sv, w2vs, w2vv0, w2vv1,
                                      WalphaT, WsvalT, WsvlinT, WvvalT, WvvlinT, WgT, WrbfT,
                                      adotB, w2B, flags);

    int nbn = (N + 3) / 4;
    k_node<1><<<nbn, 256, 0, stream>>>(node, gs, bs, gv, Wss, Wvs, Wsd, Wvd,
                                       ssrc, sdst, vsrc, vdst, flags, N);
    k_node<0><<<nbn, 256, 0, stream>>>(node, gs, bs, gv, Wss, Wvs, Wsd, Wvd,
                                       ssrc, sdst, vsrc, vdst, flags, N);

    if (fast) {
        for (long long cb = 0; cb < E; cb += chunk) {
            long long ce = cb + chunk; if (ce > E) ce = E;
            int nbc = (int)((ce - cb + 63) / 64);
            k_m1<1><<<nbc, 256, 0, stream>>>(eidx, rbf, rsh, WrbfT, ssrc, sdst, vsrc, vdst,
                                             m1buf, flags, E, cb, ce);
            k_m1<0><<<nbc, 256, 0, stream>>>(eidx, rbf, rsh, WrbfT, ssrc, sdst, vsrc, vdst,
                                             m1buf, flags, E, cb, ce);
            k_edge2<1><<<nbc, 256, 0, stream>>>(eidx, rsh, WalphaT, WsvalT, WsvlinT, WvvalT,
                                                WvvlinT, WgT, adotB, w2B, m1buf, den, agg,
                                                flags, E, cb, ce);
            k_edge2<0><<<nbc, 256, 0, stream>>>(eidx, rsh, WalphaT, WsvalT, WsvlinT, WvvalT,
                                                WvvlinT, WgT, adotB, w2B, m1buf, den, agg,
                                                flags, E, cb, ce);
        }
    } else {
        int nb = (E + 63) / 64;
        k_edge_fused<1><<<nb, 256, 0, stream>>>(eidx, rbf, rsh,
                                      WalphaT, WsvalT, WsvlinT, WvvalT, WvvlinT, WgT, WrbfT,
                                      adotB, w2B, ssrc, sdst, vsrc, vdst, den, agg, flags, E);
        k_edge_fused<0><<<nb, 256, 0, stream>>>(eidx, rbf, rsh,
                                      WalphaT, WsvalT, WsvlinT, WvvalT, WvvlinT, WgT, WrbfT,
                                      adotB, w2B, ssrc, sdst, vsrc, vdst, den, agg, flags, E);
    }

    int nbo = (N + 3) / 4;
    k_out<1><<<nbo, 256, 0, stream>>>(node, den, agg, Wps, Wpv, d_out, flags, N);
    k_out<0><<<nbo, 256, 0, stream>>>(node, den, agg, Wps, Wpv, d_out, flags, N);
}

// Round 7
// 889.775 us; speedup vs baseline: 2.6536x; 2.6536x over previous
//
#include <hip/hip_runtime.h>
#include <hip/hip_bf16.h>
#include <cstddef>

typedef __hip_bfloat16 bf16;
typedef __bf16 bfv8 __attribute__((ext_vector_type(8)));
typedef float f4 __attribute__((ext_vector_type(4)));

#define EPSN 1e-5f
#define SQRT3_INV 0.57735026918962576f
#define SQRT2_INV 0.70710678118654752f

__device__ __forceinline__ float b2f(bf16 x) { return __bfloat162float(x); }

template<int BF> __device__ __forceinline__ float ldf(const void* p, size_t i) {
    if (BF) return __bfloat162float(((const bf16*)p)[i]);
    return ((const float*)p)[i];
}
__device__ __forceinline__ float ldr(const void* p, size_t i, int bfm) {
    return bfm ? __bfloat162float(((const bf16*)p)[i]) : ((const float*)p)[i];
}
template<int BF> __device__ __forceinline__ void stf(void* p, size_t i, float v) {
    if (BF) ((bf16*)p)[i] = __float2bfloat16(v);
    else    ((float*)p)[i] = v;
}

__device__ __forceinline__ float wave_sum64(float x) {
    #pragma unroll
    for (int m = 1; m < 64; m <<= 1) x += __shfl_xor(x, m, 64);
    return x;
}

__device__ __forceinline__ f4 mf(bfv8 a, bfv8 b, f4 c) {
    return __builtin_amdgcn_mfma_f32_16x16x32_bf16(a, b, c, 0, 0, 0);
}

// ---------------- Sniffer ----------------
__global__ __launch_bounds__(256) void k_sniff(const void* node, const void* eidx, int* flags)
{
    int t = threadIdx.x;
    __shared__ int cnt;
    __shared__ unsigned orr;
    if (t == 0) { cnt = 0; orr = 0u; }
    __syncthreads();
    unsigned w  = ((const unsigned*)node)[t];
    unsigned lo = w & 0xFFFFu;
    int e_lo = (int)((lo >> 7) & 0xFF);
    if (e_lo >= 96 && e_lo <= 140) atomicAdd(&cnt, 1);
    unsigned odd = ((const unsigned*)eidx)[2 * t + 1];
    atomicOr(&orr, odd);
    __syncthreads();
    if (t == 0) {
        flags[0] = (cnt >= 128) ? 1 : 0;   // 1 = bf16 inputs
        flags[1] = (orr == 0u) ? 1 : 0;    // 1 = int64 edge_index
    }
}

__global__ __launch_bounds__(256) void k_zero(float* p, int n)
{
    int i = blockIdx.x * 256 + threadIdx.x;
    if (i < n) p[i] = 0.f;
}

// ---------------- Prep: transpose weights to bf16 [n][k] ----------------
template<int BF>
__device__ __forceinline__ void prep_impl(
    const void* Walpha, const void* Wsval, const void* Wsvlin,
    const void* Wvval, const void* Wvvlin, const void* Wg,
    const void* Wrbf, const void* adot,
    const void* w2ss, const void* w2sv, const void* w2vs,
    const void* w2vv0, const void* w2vv1,
    bf16* WalphaT, bf16* WsvalT, bf16* WsvlinT,
    bf16* WvvalT, bf16* WvvlinT, bf16* WgT,
    bf16* WrbfT, bf16* adotB, bf16* w2B)
{
    int t = threadIdx.x + blockIdx.x * 256;
    int T = gridDim.x * 256;
    for (int i = t; i < 96 * 64; i += T) {
        int c = i >> 6, n = i & 63;
        WalphaT[n * 96 + c] = __float2bfloat16(ldf<BF>(Walpha, i));
        WsvalT [n * 96 + c] = __float2bfloat16(ldf<BF>(Wsval,  i));
        WsvlinT[n * 96 + c] = __float2bfloat16(ldf<BF>(Wsvlin, i));
    }
    for (int i = t; i < 128 * 32; i += T) {
        int c = i >> 5, n = i & 31;
        WvvalT [n * 128 + c] = __float2bfloat16(ldf<BF>(Wvval,  i));
        WvvlinT[n * 128 + c] = __float2bfloat16(ldf<BF>(Wvvlin, i));
    }
    for (int i = t; i < 64 * 32; i += T) {
        int c = i >> 5, n = i & 31;
        WgT[n * 64 + c] = __float2bfloat16(ldf<BF>(Wg, i));
    }
    for (int i = t; i < 16 * 224; i += T) {
        int b = i / 224, c = i - b * 224;
        WrbfT[c * 16 + b] = __float2bfloat16(ldf<BF>(Wrbf, i));
    }
    if (t < 64) adotB[t] = __float2bfloat16(ldf<BF>(adot, t));
    if (t < 64) w2B[t]      = __float2bfloat16(ldf<BF>(w2ss, t));
    if (t < 64) w2B[64 + t] = __float2bfloat16(ldf<BF>(w2sv, t));
    if (t < 32) {
        w2B[128 + t] = __float2bfloat16(ldf<BF>(w2vs, t));
        w2B[160 + t] = __float2bfloat16(ldf<BF>(w2vv0, t));
        w2B[192 + t] = __float2bfloat16(ldf<BF>(w2vv1, t));
    }
}

__global__ __launch_bounds__(256) void k_prep(
    const void* Walpha, const void* Wsval, const void* Wsvlin,
    const void* Wvval, const void* Wvvlin, const void* Wg,
    const void* Wrbf, const void* adot,
    const void* w2ss, const void* w2sv, const void* w2vs,
    const void* w2vv0, const void* w2vv1,
    bf16* WalphaT, bf16* WsvalT, bf16* WsvlinT,
    bf16* WvvalT, bf16* WvvlinT, bf16* WgT,
    bf16* WrbfT, bf16* adotB, bf16* w2B, const int* flags)
{
    if (flags[0])
        prep_impl<1>(Walpha, Wsval, Wsvlin, Wvval, Wvvlin, Wg, Wrbf, adot,
                     w2ss, w2sv, w2vs, w2vv0, w2vv1,
                     WalphaT, WsvalT, WsvlinT, WvvalT, WvvlinT, WgT, WrbfT, adotB, w2B);
    else
        prep_impl<0>(Walpha, Wsval, Wsvlin, Wvval, Wvvlin, Wg, Wrbf, adot,
                     w2ss, w2sv, w2vs, w2vv0, w2vv1,
                     WalphaT, WsvalT, WsvlinT, WvvalT, WvvlinT, WgT, WrbfT, adotB, w2B);
}

// ---------------- Kernel 1: per-node layernorm + projections (4 nodes/block) ----------------
template<int BF>
__device__ __forceinline__ void node_impl(
    const void* node, const void* gs, const void* bs, const void* gv,
    const void* Wss, const void* Wvs, const void* Wsd, const void* Wvd,
    bf16* ssrc, bf16* sdst, bf16* vsrc, bf16* vdst,
    float* shs, float* shv, int n, int lane)
{
    size_t nb = (size_t)n * 160;

    float s  = ldf<BF>(node, nb + lane);
    float mu = wave_sum64(s) * (1.f / 64.f);
    float d  = s - mu;
    float var = wave_sum64(d * d) * (1.f / 64.f);
    float sn  = d * rsqrtf(var + EPSN) * ldf<BF>(gs, lane) + ldf<BF>(bs, lane);
    shs[lane] = sn;

    float v0 = 0.f, v1 = 0.f, v2 = 0.f, q = 0.f;
    if (lane < 32) {
        v0 = ldf<BF>(node, nb + 64 + lane * 3 + 0);
        v1 = ldf<BF>(node, nb + 64 + lane * 3 + 1);
        v2 = ldf<BF>(node, nb + 64 + lane * 3 + 2);
        q = v0 * v0 + v1 * v1 + v2 * v2;
    }
    float msq = wave_sum64(q) * (1.f / 32.f);
    float inv = rsqrtf(msq + EPSN);
    if (lane < 32) {
        float g = ldf<BF>(gv, lane);
        shv[0 * 32 + lane] = v0 * inv * g;
        shv[1 * 32 + lane] = v1 * inv * g;
        shv[2 * 32 + lane] = v2 * inv * g;
    }
    // same-wave LDS write->read: in-order, no barrier needed

    float a1 = 0.f, a2 = 0.f;
    for (int c = 0; c < 64; ++c) {
        float sc = shs[c];
        a1 += sc * ldf<BF>(Wss, c * 64 + lane);
        a2 += sc * ldf<BF>(Wsd, c * 64 + lane);
    }
    ssrc[(size_t)n * 64 + lane] = __float2bfloat16(a1);
    sdst[(size_t)n * 64 + lane] = __float2bfloat16(a2);

    {
        int x = lane >> 5, dd = lane & 31;
        float p1 = 0.f, p2 = 0.f;
        for (int c = 0; c < 32; ++c) {
            float vc = shv[x * 32 + c];
            p1 += vc * ldf<BF>(Wvs, c * 32 + dd);
            p2 += vc * ldf<BF>(Wvd, c * 32 + dd);
        }
        vsrc[(size_t)n * 96 + x * 32 + dd] = __float2bfloat16(p1);
        vdst[(size_t)n * 96 + x * 32 + dd] = __float2bfloat16(p2);
    }
    if (lane < 32) {
        int dd = lane;
        float p1 = 0.f, p2 = 0.f;
        for (int c = 0; c < 32; ++c) {
            float vc = shv[2 * 32 + c];
            p1 += vc * ldf<BF>(Wvs, c * 32 + dd);
            p2 += vc * ldf<BF>(Wvd, c * 32 + dd);
        }
        vsrc[(size_t)n * 96 + 64 + dd] = __float2bfloat16(p1);
        vdst[(size_t)n * 96 + 64 + dd] = __float2bfloat16(p2);
    }
}

__global__ __launch_bounds__(256) void k_node(
    const void* node, const void* gs, const void* bs, const void* gv,
    const void* Wss, const void* Wvs, const void* Wsd, const void* Wvd,
    bf16* ssrc, bf16* sdst, bf16* vsrc, bf16* vdst,
    const int* flags, int N)
{
    __shared__ float shs[4][64];
    __shared__ float shv[4][96];
    int wv = threadIdx.x >> 6, lane = threadIdx.x & 63;
    int n = blockIdx.x * 4 + wv; if (n >= N) return;
    if (flags[0])
        node_impl<1>(node, gs, bs, gv, Wss, Wvs, Wsd, Wvd, ssrc, sdst, vsrc, vdst,
                     shs[wv], shv[wv], n, lane);
    else
        node_impl<0>(node, gs, bs, gv, Wss, Wvs, Wsd, Wvd, ssrc, sdst, vsrc, vdst,
                     shs[wv], shv[wv], n, lane);
}

// ---------------- Kernel 2: fused MFMA edge pass, hoisted gather ----------------
// LDS per wave (bf16 elems): A1S [16][104] m1/m2_s; A1V 3x[16][136] m1/m2_v; VAL [16][72] pre-sigmoid val_s
static constexpr int A1S = 0,    SS = 104;
static constexpr int A1V = 1664, PV = 2176, SV = 136;
static constexpr int VAL = 8192, SA = 72;
static constexpr int HSZ = 9344;

__global__ __launch_bounds__(256, 2) void k_edge(
    const void* __restrict__ eidx, const void* __restrict__ rbf, const void* __restrict__ rsh,
    const bf16* __restrict__ WalphaT, const bf16* __restrict__ WsvalT, const bf16* __restrict__ WsvlinT,
    const bf16* __restrict__ WvvalT, const bf16* __restrict__ WvvlinT, const bf16* __restrict__ WgT,
    const bf16* __restrict__ WrbfT, const bf16* __restrict__ adotB, const bf16* __restrict__ w2B,
    const bf16* __restrict__ ssrc, const bf16* __restrict__ sdst,
    const bf16* __restrict__ vsrc, const bf16* __restrict__ vdst,
    float* __restrict__ den, float* __restrict__ agg,
    const int* __restrict__ flags, int E)
{
    const int bfm = flags[0];
    const int i64 = flags[1];

    __shared__ __align__(16) __bf16 sH[4][HSZ];
    __shared__ __align__(16) float sRbf[4][16][20];
    __shared__ __align__(16) float sY[4][16][4];
    __shared__ int sSD[4][32];   // [0..15]=src, [16..31]=dst

    int wv = threadIdx.x >> 6, l = threadIdx.x & 63;
    int q = l >> 4, m = l & 15;
    long long eb = ((long long)blockIdx.x * 4 + wv) * 16;
    if (eb >= E) return;        // wave-uniform; no barriers
    __bf16* H = &sH[wv][0];

    // ---- edge metadata ----
    if (l < 32) {
        long long ee = eb + (l & 15); if (ee > (long long)E - 1) ee = E - 1;
        long long off = (l < 16) ? ee : ((long long)E + ee);
        sSD[wv][l] = i64 ? (int)((const long long*)eidx)[off] : ((const int*)eidx)[off];
    }
    {
        long long ee = eb + (l >> 2); if (ee > (long long)E - 1) ee = E - 1;
        sY[wv][l >> 2][l & 3] = ldr(rsh, (size_t)ee * 4 + (l & 3), bfm);
    }
    #pragma unroll
    for (int j = 0; j < 4; ++j) {
        long long ee = eb + j * 4 + q; if (ee > (long long)E - 1) ee = E - 1;
        sRbf[wv][m][j * 4 + q] = ldr(rbf, (size_t)ee * 16 + m, bfm);
    }

    // ---- WrbfT fragments ----
    const __bf16* wrt = (const __bf16*)WrbfT;
    int lv = l & 31;
    bfv8 w0a = *(const bfv8*)(wrt + l * 16);
    bfv8 w0b = *(const bfv8*)(wrt + l * 16 + 8);
    bfv8 w1a = *(const bfv8*)(wrt + (64 + l) * 16);
    bfv8 w1b = *(const bfv8*)(wrt + (64 + l) * 16 + 8);
    bfv8 w2a = *(const bfv8*)(wrt + (128 + lv) * 16);
    bfv8 w2b = *(const bfv8*)(wrt + (128 + lv) * 16 + 8);
    bfv8 w3a = *(const bfv8*)(wrt + (160 + lv) * 16);
    bfv8 w3b = *(const bfv8*)(wrt + (160 + lv) * 16 + 8);
    bfv8 w4a = *(const bfv8*)(wrt + (192 + lv) * 16);
    bfv8 w4b = *(const bfv8*)(wrt + (192 + lv) * 16 + 8);

    // ---- S1: HOISTED gather (8 edges/round) + w1 + m1 tensor product -> LDS ----
    #pragma unroll 1
    for (int h = 0; h < 2; ++h) {
        bf16 rS[8], rD[8], rv[6][8];
        #pragma unroll
        for (int k = 0; k < 8; ++k) {
            int s = sSD[wv][8 * h + k], d = sSD[wv][16 + 8 * h + k];
            rS[k] = ssrc[(size_t)s * 64 + l];
            rD[k] = sdst[(size_t)d * 64 + l];
            if (l < 32) {
                rv[0][k] = vsrc[(size_t)s * 96 +      l];
                rv[1][k] = vsrc[(size_t)s * 96 + 32 + l];
                rv[2][k] = vsrc[(size_t)s * 96 + 64 + l];
                rv[3][k] = vdst[(size_t)d * 96 +      l];
                rv[4][k] = vdst[(size_t)d * 96 + 32 + l];
                rv[5][k] = vdst[(size_t)d * 96 + 64 + l];
            }
        }
        #pragma unroll
        for (int j2 = 0; j2 < 2; ++j2) {
            int jj = 2 * h + j2;
            float y0k[4], yxk[4], yyk[4], yzk[4], ms[4];
            float mv0[4], mv1[4], mv2[4];
            #pragma unroll
            for (int k = 0; k < 4; ++k) {
                float4 yy = *(const float4*)&sY[wv][4 * jj + k][0];
                y0k[k] = yy.x; yxk[k] = yy.y; yyk[k] = yy.z; yzk[k] = yy.w;
                int kk = 4 * j2 + k;
                ms[k]  = b2f(rS[kk]) + b2f(rD[kk]);
                mv0[k] = b2f(rv[0][kk]) + b2f(rv[3][kk]);   // valid lanes<32 only
                mv1[k] = b2f(rv[1][kk]) + b2f(rv[4][kk]);
                mv2[k] = b2f(rv[2][kk]) + b2f(rv[5][kk]);
            }
            float wss[4] = {0,0,0,0}, wsv[4] = {0,0,0,0};
            float wvs[4] = {0,0,0,0}, wv0[4] = {0,0,0,0}, wv1[4] = {0,0,0,0};
            #pragma unroll
            for (int b = 0; b < 16; ++b) {
                float2 ra = *(const float2*)&sRbf[wv][b][4 * jj];
                float2 rb = *(const float2*)&sRbf[wv][b][4 * jj + 2];
                float r0 = ra.x, r1 = ra.y, r2 = rb.x, r3 = rb.y;
                float wa  = (float)(b < 8 ? w0a[b] : w0b[b - 8]);
                float wb_ = (float)(b < 8 ? w1a[b] : w1b[b - 8]);
                float wc  = (float)(b < 8 ? w2a[b] : w2b[b - 8]);
                float wd  = (float)(b < 8 ? w3a[b] : w3b[b - 8]);
                float we  = (float)(b < 8 ? w4a[b] : w4b[b - 8]);
                wss[0] += r0 * wa;  wss[1] += r1 * wa;  wss[2] += r2 * wa;  wss[3] += r3 * wa;
                wsv[0] += r0 * wb_; wsv[1] += r1 * wb_; wsv[2] += r2 * wb_; wsv[3] += r3 * wb_;
                wvs[0] += r0 * wc;  wvs[1] += r1 * wc;  wvs[2] += r2 * wc;  wvs[3] += r3 * wc;
                wv0[0] += r0 * wd;  wv0[1] += r1 * wd;  wv0[2] += r2 * wd;  wv0[3] += r3 * wd;
                wv1[0] += r0 * we;  wv1[1] += r1 * we;  wv1[2] += r2 * we;  wv1[3] += r3 * we;
            }
            #pragma unroll
            for (int k = 0; k < 4; ++k) {
                int e = 4 * jj + k;
                H[A1S + e * SS + l] = (__bf16)(wss[k] * ms[k] * y0k[k]);
                float sv = wsv[k] * ms[k];
                H[A1V + 0 * PV + e * SV + l] = (__bf16)(sv * yxk[k]);
                H[A1V + 1 * PV + e * SV + l] = (__bf16)(sv * yyk[k]);
                H[A1V + 2 * PV + e * SV + l] = (__bf16)(sv * yzk[k]);
            }
            if (l < 32) {
                #pragma unroll
                for (int k = 0; k < 4; ++k) {
                    int e = 4 * jj + k;
                    H[A1S + e * SS + 64 + l] =
                        (__bf16)(wv0[k] * (mv0[k] * yxk[k] + mv1[k] * yyk[k] + mv2[k] * yzk[k]) * SQRT3_INV);
                    H[A1V + 0 * PV + e * SV + 64 + l] = (__bf16)(wvs[k] * mv0[k] * y0k[k]);
                    H[A1V + 1 * PV + e * SV + 64 + l] = (__bf16)(wvs[k] * mv1[k] * y0k[k]);
                    H[A1V + 2 * PV + e * SV + 64 + l] = (__bf16)(wvs[k] * mv2[k] * y0k[k]);
                    float cx = mv1[k] * yzk[k] - mv2[k] * yyk[k];
                    float cy = mv2[k] * yxk[k] - mv0[k] * yzk[k];
                    float cz = mv0[k] * yyk[k] - mv1[k] * yxk[k];
                    H[A1V + 0 * PV + e * SV + 96 + l] = (__bf16)(wv1[k] * cx * SQRT2_INV);
                    H[A1V + 1 * PV + e * SV + 96 + l] = (__bf16)(wv1[k] * cy * SQRT2_INV);
                    H[A1V + 2 * PV + e * SV + 96 + l] = (__bf16)(wv1[k] * cz * SQRT2_INV);
                }
            }
        }
    }

    const int kq = q * 8;

    // ---- S2: val_s = m1_s @ Ws_val; PRE-sigmoid -> VAL, sigmoid -> regs ----
    bfv8 a1s0 = *(const bfv8*)(H + A1S + m * SS + 0  + kq);
    bfv8 a1s1 = *(const bfv8*)(H + A1S + m * SS + 32 + kq);
    bfv8 a1s2 = *(const bfv8*)(H + A1S + m * SS + 64 + kq);
    f4 vals[4];
    #pragma unroll
    for (int nt = 0; nt < 4; ++nt) {
        const __bf16* bp = (const __bf16*)WsvalT + (size_t)(nt * 16 + m) * 96 + kq;
        f4 acc = {0.f, 0.f, 0.f, 0.f};
        acc = mf(a1s0, *(const bfv8*)(bp),      acc);
        acc = mf(a1s1, *(const bfv8*)(bp + 32), acc);
        acc = mf(a1s2, *(const bfv8*)(bp + 64), acc);
        vals[nt] = acc;
    }
    #pragma unroll
    for (int nt = 0; nt < 4; ++nt)
        #pragma unroll
        for (int r = 0; r < 4; ++r) {
            float v = vals[nt][r];
            H[VAL + (q * 4 + r) * SA + nt * 16 + m] = (__bf16)v;   // PRE-sigmoid
            vals[nt][r] = 1.f / (1.f + __expf(-v));
        }

    // ---- S3: gate = sigmoid(val_s_pre @ Wg) ----
    bfv8 av0 = *(const bfv8*)(H + VAL + m * SA + 0  + kq);
    bfv8 av1 = *(const bfv8*)(H + VAL + m * SA + 32 + kq);
    f4 gate[2];
    #pragma unroll
    for (int nt = 0; nt < 2; ++nt) {
        const __bf16* bp = (const __bf16*)WgT + (size_t)(nt * 16 + m) * 64 + kq;
        f4 acc = {0.f, 0.f, 0.f, 0.f};
        acc = mf(av0, *(const bfv8*)(bp),      acc);
        acc = mf(av1, *(const bfv8*)(bp + 32), acc);
        gate[nt] = acc;
    }
    #pragma unroll
    for (int nt = 0; nt < 2; ++nt)
        #pragma unroll
        for (int r = 0; r < 4; ++r)
            gate[nt][r] = 1.f / (1.f + __expf(-gate[nt][r]));

    // ---- S4: attention logits + ex (den-restructured softmax) ----
    float ex_[4][4];
    #pragma unroll
    for (int nt = 0; nt < 4; ++nt) {
        const __bf16* bp = (const __bf16*)WalphaT + (size_t)(nt * 16 + m) * 96 + kq;
        f4 acc = {0.f, 0.f, 0.f, 0.f};
        acc = mf(a1s0, *(const bfv8*)(bp),      acc);
        acc = mf(a1s1, *(const bfv8*)(bp + 32), acc);
        acc = mf(a1s2, *(const bfv8*)(bp + 64), acc);
        float ad = b2f(adotB[nt * 16 + m]);
        #pragma unroll
        for (int r = 0; r < 4; ++r) {
            float tv = acc[r];
            tv = tv > 0.f ? tv : 0.2f * tv;
            tv *= ad;
            tv += __shfl_xor(tv, 1); tv += __shfl_xor(tv, 2);
            tv += __shfl_xor(tv, 4); tv += __shfl_xor(tv, 8);
            tv = fminf(fmaxf(tv, -60.f), 60.f);
            ex_[nt][r] = __expf(tv);
        }
    }

    // ---- S5: val_v = (m1_v @ Wv_val) * gate ----
    bfv8 a1v[3][4];
    #pragma unroll
    for (int x = 0; x < 3; ++x)
        #pragma unroll
        for (int kt = 0; kt < 4; ++kt)
            a1v[x][kt] = *(const bfv8*)(H + A1V + x * PV + m * SV + kt * 32 + kq);
    f4 vv[3][2];
    #pragma unroll
    for (int x = 0; x < 3; ++x)
        #pragma unroll
        for (int nt = 0; nt < 2; ++nt)
            vv[x][nt] = (f4){0.f, 0.f, 0.f, 0.f};
    #pragma unroll
    for (int nt = 0; nt < 2; ++nt) {
        const __bf16* bp = (const __bf16*)WvvalT + (size_t)(nt * 16 + m) * 128 + kq;
        #pragma unroll
        for (int kt = 0; kt < 4; ++kt) {
            bfv8 b = *(const bfv8*)(bp + kt * 32);
            vv[0][nt] = mf(a1v[0][kt], b, vv[0][nt]);
            vv[1][nt] = mf(a1v[1][kt], b, vv[1][nt]);
            vv[2][nt] = mf(a1v[2][kt], b, vv[2][nt]);
        }
    }
    #pragma unroll
    for (int x = 0; x < 3; ++x)
        #pragma unroll
        for (int nt = 0; nt < 2; ++nt)
            #pragma unroll
            for (int r = 0; r < 4; ++r)
                vv[x][nt][r] *= gate[nt][r];

    // ---- S6: m2 tensor product -> LDS (reuse m1 buffers) ----
    float c2ss[4], c2sv[4];
    #pragma unroll
    for (int nt = 0; nt < 4; ++nt) {
        c2ss[nt] = b2f(w2B[nt * 16 + m]);
        c2sv[nt] = b2f(w2B[64 + nt * 16 + m]);
    }
    float c2vs[2], c2v0[2], c2v1[2];
    #pragma unroll
    for (int nt = 0; nt < 2; ++nt) {
        c2vs[nt] = b2f(w2B[128 + nt * 16 + m]);
        c2v0[nt] = b2f(w2B[160 + nt * 16 + m]);
        c2v1[nt] = b2f(w2B[192 + nt * 16 + m]);
    }
    #pragma unroll
    for (int r = 0; r < 4; ++r) {
        int e = q * 4 + r;
        float4 yy = *(const float4*)&sY[wv][e][0];
        float y0 = yy.x, yx = yy.y, yh = yy.z, yz = yy.w;
        int rS  = A1S + e * SS;
        int rV0 = A1V + 0 * PV + e * SV;
        int rV1 = A1V + 1 * PV + e * SV;
        int rV2 = A1V + 2 * PV + e * SV;
        #pragma unroll
        for (int nt = 0; nt < 4; ++nt) {
            int c = nt * 16 + m;
            float va = vals[nt][r];
            H[rS + c] = (__bf16)(c2ss[nt] * va * y0);
            float t2 = c2sv[nt] * va;
            H[rV0 + c] = (__bf16)(t2 * yx);
            H[rV1 + c] = (__bf16)(t2 * yh);
            H[rV2 + c] = (__bf16)(t2 * yz);
        }
        #pragma unroll
        for (int nt = 0; nt < 2; ++nt) {
            int c = nt * 16 + m;
            float v0 = vv[0][nt][r], v1 = vv[1][nt][r], v2 = vv[2][nt][r];
            H[rS + 64 + c] = (__bf16)(c2v0[nt] * (v0 * yx + v1 * yh + v2 * yz) * SQRT3_INV);
            H[rV0 + 64 + c] = (__bf16)(c2vs[nt] * v0 * y0);
            H[rV1 + 64 + c] = (__bf16)(c2vs[nt] * v1 * y0);
            H[rV2 + 64 + c] = (__bf16)(c2vs[nt] * v2 * y0);
            float cx = v1 * yz - v2 * yh;
            float cy = v2 * yx - v0 * yz;
            float cz = v0 * yh - v1 * yx;
            H[rV0 + 96 + c] = (__bf16)(c2v1[nt] * cx * SQRT2_INV);
            H[rV1 + 96 + c] = (__bf16)(c2v1[nt] * cy * SQRT2_INV);
            H[rV2 + 96 + c] = (__bf16)(c2v1[nt] * cz * SQRT2_INV);
        }
    }

    // ---- S7: h projections ----
    bfv8 a2s0 = *(const bfv8*)(H + A1S + m * SS + 0  + kq);
    bfv8 a2s1 = *(const bfv8*)(H + A1S + m * SS + 32 + kq);
    bfv8 a2s2 = *(const bfv8*)(H + A1S + m * SS + 64 + kq);
    f4 hs[4];
    #pragma unroll
    for (int nt = 0; nt < 4; ++nt) {
        const __bf16* bp = (const __bf16*)WsvlinT + (size_t)(nt * 16 + m) * 96 + kq;
        f4 acc = {0.f, 0.f, 0.f, 0.f};
        acc = mf(a2s0, *(const bfv8*)(bp),      acc);
        acc = mf(a2s1, *(const bfv8*)(bp + 32), acc);
        acc = mf(a2s2, *(const bfv8*)(bp + 64), acc);
        hs[nt] = acc;
    }
    bfv8 a2v[3][4];
    #pragma unroll
    for (int x = 0; x < 3; ++x)
        #pragma unroll
        for (int kt = 0; kt < 4; ++kt)
            a2v[x][kt] = *(const bfv8*)(H + A1V + x * PV + m * SV + kt * 32 + kq);
    f4 hv[3][2];
    #pragma unroll
    for (int x = 0; x < 3; ++x)
        #pragma unroll
        for (int nt = 0; nt < 2; ++nt)
            hv[x][nt] = (f4){0.f, 0.f, 0.f, 0.f};
    #pragma unroll
    for (int nt = 0; nt < 2; ++nt) {
        const __bf16* bp = (const __bf16*)WvvlinT + (size_t)(nt * 16 + m) * 128 + kq;
        #pragma unroll
        for (int kt = 0; kt < 4; ++kt) {
            bfv8 b = *(const bfv8*)(bp + kt * 32);
            hv[0][nt] = mf(a2v[0][kt], b, hv[0][nt]);
            hv[1][nt] = mf(a2v[1][kt], b, hv[1][nt]);
            hv[2][nt] = mf(a2v[2][kt], b, hv[2][nt]);
        }
    }

    // ---- S8: scatter ----
    #pragma unroll
    for (int r = 0; r < 4; ++r) {
        int e = q * 4 + r;
        long long eg = eb + e;
        if (eg < E) {
            int d = sSD[wv][16 + e];
            float* rowp = agg + (size_t)d * 160;
            if (m < 4) {
                float exm = (m == 0) ? ex_[0][r] : (m == 1) ? ex_[1][r] : (m == 2) ? ex_[2][r] : ex_[3][r];
                unsafeAtomicAdd(den + (size_t)d * 4 + m, exm);
            }
            #pragma unroll
            for (int nt = 0; nt < 4; ++nt)
                unsafeAtomicAdd(rowp + nt * 40 + m, ex_[nt][r] * hs[nt][r]);
            #pragma unroll
            for (int nt = 0; nt < 2; ++nt) {
                int c = nt * 16 + m;
                int hh = c >> 3, dd = c & 7;
                float exv = (m >= 8) ? ex_[2 * nt + 1][r] : ex_[2 * nt][r];
                float* vb = rowp + hh * 40 + 16 + dd * 3;
                unsafeAtomicAdd(vb + 0, exv * hv[0][nt][r]);
                unsafeAtomicAdd(vb + 1, exv * hv[1][nt][r]);
                unsafeAtomicAdd(vb + 2, exv * hv[2][nt][r]);
            }
        }
    }
}

// ---------------- Kernel 3: normalize + output projection + residual (4 nodes/block) ----------------
template<int BF>
__device__ __forceinline__ void out_impl(
    const void* node, const float* den, const float* agg,
    const void* Wps, const void* Wpv, void* out,
    float* shs, float* shv, float* sinv, int n, int lane)
{
    if (lane < 4) sinv[lane] = 1.f / (den[(size_t)n * 4 + lane] + 1e-16f);
    for (int idx = lane; idx < 160; idx += 64) {
        int h = idx / 40, r = idx - h * 40;
        float val = agg[(size_t)n * 160 + idx] * sinv[h];
        if (r < 16) shs[h * 16 + r] = val;
        else { int rr = r - 16; int dd = rr / 3, x = rr - dd * 3; shv[x * 32 + h * 8 + dd] = val; }
    }

    float acc = ldf<BF>(node, (size_t)n * 160 + lane);
    for (int c = 0; c < 64; ++c) acc += shs[c] * ldf<BF>(Wps, c * 64 + lane);
    stf<BF>(out, (size_t)n * 160 + lane, acc);

    {
        int idx = lane; int dd = idx / 3, x = idx - dd * 3;
        float a = ldf<BF>(node, (size_t)n * 160 + 64 + idx);
        for (int c = 0; c < 32; ++c) a += shv[x * 32 + c] * ldf<BF>(Wpv, c * 32 + dd);
        stf<BF>(out, (size_t)n * 160 + 64 + idx, a);
    }
    if (lane < 32) {
        int idx = 64 + lane; int dd = idx / 3, x = idx - dd * 3;
        float a = ldf<BF>(node, (size_t)n * 160 + 64 + idx);
        for (int c = 0; c < 32; ++c) a += shv[x * 32 + c] * ldf<BF>(Wpv, c * 32 + dd);
        stf<BF>(out, (size_t)n * 160 + 64 + idx, a);
    }
}

__global__ __launch_bounds__(256) void k_out(
    const void* node, const float* den, const float* agg,
    const void* Wps, const void* Wpv, void* out,
    const int* flags, int N)
{
    __shared__ float shs[4][64];
    __shared__ float shv[4][96];
    __shared__ float sinv[4][4];
    int wv = threadIdx.x >> 6, lane = threadIdx.x & 63;
    int n = blockIdx.x * 4 + wv; if (n >= N) return;
    if (flags[0])
        out_impl<1>(node, den, agg, Wps, Wpv, out, shs[wv], shv[wv], sinv[wv], n, lane);
    else
        out_impl<0>(node, den, agg, Wps, Wpv, out, shs[wv], shv[wv], sinv[wv], n, lane);
}

// ---------------- Launch ----------------
extern "C" void kernel_launch(void* const* d_in, const int* in_sizes, int n_in,
                              void* d_out, int out_size, void* d_ws, size_t ws_size,
                              hipStream_t stream)
{
    const void* node   = d_in[0];
    const void* eidx   = d_in[1];
    const void* rbf    = d_in[2];
    const void* rsh    = d_in[3];
    const void* gs     = d_in[4];
    const void* bs     = d_in[5];
    const void* gv     = d_in[6];
    const void* Wss    = d_in[7];
    const void* Wvs    = d_in[8];
    const void* Wsd    = d_in[9];
    const void* Wvd    = d_in[10];
    const void* Wrbf   = d_in[11];
    const void* Walpha = d_in[12];
    const void* adot   = d_in[13];
    const void* Wsval  = d_in[14];
    const void* Wvval  = d_in[15];
    const void* Wg     = d_in[16];
    const void* w2ss   = d_in[17];
    const void* w2sv   = d_in[18];
    const void* w2vs   = d_in[19];
    const void* w2vv0  = d_in[20];
    const void* w2vv1  = d_in[21];
    const void* Wsvlin = d_in[22];
    const void* Wvvlin = d_in[23];
    const void* Wps    = d_in[24];
    const void* Wpv    = d_in[25];

    int N = in_sizes[0] / 160;
    int E = in_sizes[1] / 2;

    char* base = (char*)d_ws;
    int*  flags   = (int*)base;                  // 16 B
    bf16* WalphaT = (bf16*)(base + 16);
    bf16* WsvalT  = WalphaT + 6144;
    bf16* WsvlinT = WsvalT  + 6144;
    bf16* WvvalT  = WsvlinT + 6144;
    bf16* WvvlinT = WvvalT  + 4096;
    bf16* WgT     = WvvlinT + 4096;
    bf16* WrbfT   = WgT     + 2048;
    bf16* adotB   = WrbfT   + 3584;
    bf16* w2B     = adotB   + 64;
    bf16* ssrc    = w2B     + 224;
    bf16* sdst    = ssrc + (size_t)N * 64;
    bf16* vsrc    = sdst + (size_t)N * 64;
    bf16* vdst    = vsrc + (size_t)N * 96;
    float* den    = (float*)(vdst + (size_t)N * 96);
    float* agg    = den + (size_t)N * 4;

    k_sniff<<<1, 256, 0, stream>>>(node, eidx, flags);
    int zn = N * 164;
    k_zero<<<(zn + 255) / 256, 256, 0, stream>>>(den, zn);

    k_prep<<<16, 256, 0, stream>>>(Walpha, Wsval, Wsvlin, Wvval, Wvvlin, Wg, Wrbf, adot,
                                   w2ss, w2sv, w2vs, w2vv0, w2vv1,
                                   WalphaT, WsvalT, WsvlinT, WvvalT, WvvlinT, WgT, WrbfT,
                                   adotB, w2B, flags);

    int nbn = (N + 3) / 4;
    k_node<<<nbn, 256, 0, stream>>>(node, gs, bs, gv, Wss, Wvs, Wsd, Wvd,
                                    ssrc, sdst, vsrc, vdst, flags, N);

    int nb = (E + 63) / 64;
    k_edge<<<nb, 256, 0, stream>>>(eidx, rbf, rsh,
                                   WalphaT, WsvalT, WsvlinT, WvvalT, WvvlinT, WgT, WrbfT,
                                   adotB, w2B, ssrc, sdst, vsrc, vdst, den, agg, flags, E);

    int nbo = (N + 3) / 4;
    k_out<<<nbo, 256, 0, stream>>>(node, den, agg, Wps, Wpv, d_out, flags, N);
}

// Round 8
// 501.299 us; speedup vs baseline: 4.7100x; 1.7749x over previous
//
#include <hip/hip_runtime.h>
#include <hip/hip_bf16.h>
#include <cstddef>

typedef __hip_bfloat16 bf16;
typedef __bf16 bfv8 __attribute__((ext_vector_type(8)));
typedef float f4 __attribute__((ext_vector_type(4)));

#define EPSN 1e-5f
#define SQRT3_INV 0.57735026918962576f
#define SQRT2_INV 0.70710678118654752f

__device__ __forceinline__ float b2f(bf16 x) { return __bfloat162float(x); }

template<int BF> __device__ __forceinline__ float ldf(const void* p, size_t i) {
    if (BF) return __bfloat162float(((const bf16*)p)[i]);
    return ((const float*)p)[i];
}
__device__ __forceinline__ float ldr(const void* p, size_t i, int bfm) {
    return bfm ? __bfloat162float(((const bf16*)p)[i]) : ((const float*)p)[i];
}
template<int BF> __device__ __forceinline__ void stf(void* p, size_t i, float v) {
    if (BF) ((bf16*)p)[i] = __float2bfloat16(v);
    else    ((float*)p)[i] = v;
}

__device__ __forceinline__ float wave_sum64(float x) {
    #pragma unroll
    for (int m = 1; m < 64; m <<= 1) x += __shfl_xor(x, m, 64);
    return x;
}

__device__ __forceinline__ f4 mf(bfv8 a, bfv8 b, f4 c) {
    return __builtin_amdgcn_mfma_f32_16x16x32_bf16(a, b, c, 0, 0, 0);
}

// ---------------- Sniffer ----------------
__global__ __launch_bounds__(256) void k_sniff(const void* node, const void* eidx, int* flags)
{
    int t = threadIdx.x;
    __shared__ int cnt;
    __shared__ unsigned orr;
    if (t == 0) { cnt = 0; orr = 0u; }
    __syncthreads();
    unsigned w  = ((const unsigned*)node)[t];
    unsigned lo = w & 0xFFFFu;
    int e_lo = (int)((lo >> 7) & 0xFF);
    if (e_lo >= 96 && e_lo <= 140) atomicAdd(&cnt, 1);
    unsigned odd = ((const unsigned*)eidx)[2 * t + 1];
    atomicOr(&orr, odd);
    __syncthreads();
    if (t == 0) {
        flags[0] = (cnt >= 128) ? 1 : 0;   // 1 = bf16 inputs
        flags[1] = (orr == 0u) ? 1 : 0;    // 1 = int64 edge_index
    }
}

__global__ __launch_bounds__(256) void k_zero(float* p, int n)
{
    int i = blockIdx.x * 256 + threadIdx.x;
    if (i < n) p[i] = 0.f;
}

// ---------------- Counting sort by dst ----------------
__global__ __launch_bounds__(256) void k_hist(const void* eidx, int* cnt,
                                              const int* flags, int E)
{
    int e = blockIdx.x * 256 + threadIdx.x;
    if (e >= E) return;
    int d = flags[1] ? (int)((const long long*)eidx)[(long long)E + e]
                     : ((const int*)eidx)[(size_t)E + e];
    atomicAdd(&cnt[d], 1);
}

__global__ __launch_bounds__(256) void k_scan(int* cnt, int N)
{
    __shared__ int part[256];
    int t = threadIdx.x;
    int chunk = (N + 255) / 256;
    int lo = t * chunk, hi = lo + chunk; if (hi > N) hi = N; if (lo > N) lo = N;
    int sum = 0;
    for (int i = lo; i < hi; ++i) sum += cnt[i];
    part[t] = sum;
    __syncthreads();
    if (t == 0) {
        int acc = 0;
        for (int i = 0; i < 256; ++i) { int v = part[i]; part[i] = acc; acc += v; }
    }
    __syncthreads();
    int acc = part[t];
    for (int i = lo; i < hi; ++i) { int v = cnt[i]; cnt[i] = acc; acc += v; }
}

__global__ __launch_bounds__(256) void k_perm(const void* eidx, int* cnt, int* perm,
                                              const int* flags, int E)
{
    int e = blockIdx.x * 256 + threadIdx.x;
    if (e >= E) return;
    int d = flags[1] ? (int)((const long long*)eidx)[(long long)E + e]
                     : ((const int*)eidx)[(size_t)E + e];
    int pos = atomicAdd(&cnt[d], 1);
    perm[pos] = e;
}

// ---------------- Prep: transpose weights to bf16 [n][k] ----------------
template<int BF>
__device__ __forceinline__ void prep_impl(
    const void* Walpha, const void* Wsval, const void* Wsvlin,
    const void* Wvval, const void* Wvvlin, const void* Wg,
    const void* Wrbf, const void* adot,
    const void* w2ss, const void* w2sv, const void* w2vs,
    const void* w2vv0, const void* w2vv1,
    bf16* WalphaT, bf16* WsvalT, bf16* WsvlinT,
    bf16* WvvalT, bf16* WvvlinT, bf16* WgT,
    bf16* WrbfT, bf16* adotB, bf16* w2B)
{
    int t = threadIdx.x + blockIdx.x * 256;
    int T = gridDim.x * 256;
    for (int i = t; i < 96 * 64; i += T) {
        int c = i >> 6, n = i & 63;
        WalphaT[n * 96 + c] = __float2bfloat16(ldf<BF>(Walpha, i));
        WsvalT [n * 96 + c] = __float2bfloat16(ldf<BF>(Wsval,  i));
        WsvlinT[n * 96 + c] = __float2bfloat16(ldf<BF>(Wsvlin, i));
    }
    for (int i = t; i < 128 * 32; i += T) {
        int c = i >> 5, n = i & 31;
        WvvalT [n * 128 + c] = __float2bfloat16(ldf<BF>(Wvval,  i));
        WvvlinT[n * 128 + c] = __float2bfloat16(ldf<BF>(Wvvlin, i));
    }
    for (int i = t; i < 64 * 32; i += T) {
        int c = i >> 5, n = i & 31;
        WgT[n * 64 + c] = __float2bfloat16(ldf<BF>(Wg, i));
    }
    for (int i = t; i < 16 * 224; i += T) {
        int b = i / 224, c = i - b * 224;
        WrbfT[c * 16 + b] = __float2bfloat16(ldf<BF>(Wrbf, i));
    }
    if (t < 64) adotB[t] = __float2bfloat16(ldf<BF>(adot, t));
    if (t < 64) w2B[t]      = __float2bfloat16(ldf<BF>(w2ss, t));
    if (t < 64) w2B[64 + t] = __float2bfloat16(ldf<BF>(w2sv, t));
    if (t < 32) {
        w2B[128 + t] = __float2bfloat16(ldf<BF>(w2vs, t));
        w2B[160 + t] = __float2bfloat16(ldf<BF>(w2vv0, t));
        w2B[192 + t] = __float2bfloat16(ldf<BF>(w2vv1, t));
    }
}

__global__ __launch_bounds__(256) void k_prep(
    const void* Walpha, const void* Wsval, const void* Wsvlin,
    const void* Wvval, const void* Wvvlin, const void* Wg,
    const void* Wrbf, const void* adot,
    const void* w2ss, const void* w2sv, const void* w2vs,
    const void* w2vv0, const void* w2vv1,
    bf16* WalphaT, bf16* WsvalT, bf16* WsvlinT,
    bf16* WvvalT, bf16* WvvlinT, bf16* WgT,
    bf16* WrbfT, bf16* adotB, bf16* w2B, const int* flags)
{
    if (flags[0])
        prep_impl<1>(Walpha, Wsval, Wsvlin, Wvval, Wvvlin, Wg, Wrbf, adot,
                     w2ss, w2sv, w2vs, w2vv0, w2vv1,
                     WalphaT, WsvalT, WsvlinT, WvvalT, WvvlinT, WgT, WrbfT, adotB, w2B);
    else
        prep_impl<0>(Walpha, Wsval, Wsvlin, Wvval, Wvvlin, Wg, Wrbf, adot,
                     w2ss, w2sv, w2vs, w2vv0, w2vv1,
                     WalphaT, WsvalT, WsvlinT, WvvalT, WvvlinT, WgT, WrbfT, adotB, w2B);
}

// ---------------- Kernel 1: per-node layernorm + projections (4 nodes/block) ----------------
template<int BF>
__device__ __forceinline__ void node_impl(
    const void* node, const void* gs, const void* bs, const void* gv,
    const void* Wss, const void* Wvs, const void* Wsd, const void* Wvd,
    bf16* ssrc, bf16* sdst, bf16* vsrc, bf16* vdst,
    float* shs, float* shv, int n, int lane)
{
    size_t nb = (size_t)n * 160;

    float s  = ldf<BF>(node, nb + lane);
    float mu = wave_sum64(s) * (1.f / 64.f);
    float d  = s - mu;
    float var = wave_sum64(d * d) * (1.f / 64.f);
    float sn  = d * rsqrtf(var + EPSN) * ldf<BF>(gs, lane) + ldf<BF>(bs, lane);
    shs[lane] = sn;

    float v0 = 0.f, v1 = 0.f, v2 = 0.f, q = 0.f;
    if (lane < 32) {
        v0 = ldf<BF>(node, nb + 64 + lane * 3 + 0);
        v1 = ldf<BF>(node, nb + 64 + lane * 3 + 1);
        v2 = ldf<BF>(node, nb + 64 + lane * 3 + 2);
        q = v0 * v0 + v1 * v1 + v2 * v2;
    }
    float msq = wave_sum64(q) * (1.f / 32.f);
    float inv = rsqrtf(msq + EPSN);
    if (lane < 32) {
        float g = ldf<BF>(gv, lane);
        shv[0 * 32 + lane] = v0 * inv * g;
        shv[1 * 32 + lane] = v1 * inv * g;
        shv[2 * 32 + lane] = v2 * inv * g;
    }
    // same-wave LDS write->read: in-order, no barrier needed

    float a1 = 0.f, a2 = 0.f;
    for (int c = 0; c < 64; ++c) {
        float sc = shs[c];
        a1 += sc * ldf<BF>(Wss, c * 64 + lane);
        a2 += sc * ldf<BF>(Wsd, c * 64 + lane);
    }
    ssrc[(size_t)n * 64 + lane] = __float2bfloat16(a1);
    sdst[(size_t)n * 64 + lane] = __float2bfloat16(a2);

    {
        int x = lane >> 5, dd = lane & 31;
        float p1 = 0.f, p2 = 0.f;
        for (int c = 0; c < 32; ++c) {
            float vc = shv[x * 32 + c];
            p1 += vc * ldf<BF>(Wvs, c * 32 + dd);
            p2 += vc * ldf<BF>(Wvd, c * 32 + dd);
        }
        vsrc[(size_t)n * 96 + x * 32 + dd] = __float2bfloat16(p1);
        vdst[(size_t)n * 96 + x * 32 + dd] = __float2bfloat16(p2);
    }
    if (lane < 32) {
        int dd = lane;
        float p1 = 0.f, p2 = 0.f;
        for (int c = 0; c < 32; ++c) {
            float vc = shv[2 * 32 + c];
            p1 += vc * ldf<BF>(Wvs, c * 32 + dd);
            p2 += vc * ldf<BF>(Wvd, c * 32 + dd);
        }
        vsrc[(size_t)n * 96 + 64 + dd] = __float2bfloat16(p1);
        vdst[(size_t)n * 96 + 64 + dd] = __float2bfloat16(p2);
    }
}

__global__ __launch_bounds__(256) void k_node(
    const void* node, const void* gs, const void* bs, const void* gv,
    const void* Wss, const void* Wvs, const void* Wsd, const void* Wvd,
    bf16* ssrc, bf16* sdst, bf16* vsrc, bf16* vdst,
    const int* flags, int N)
{
    __shared__ float shs[4][64];
    __shared__ float shv[4][96];
    int wv = threadIdx.x >> 6, lane = threadIdx.x & 63;
    int n = blockIdx.x * 4 + wv; if (n >= N) return;
    if (flags[0])
        node_impl<1>(node, gs, bs, gv, Wss, Wvs, Wsd, Wvd, ssrc, sdst, vsrc, vdst,
                     shs[wv], shv[wv], n, lane);
    else
        node_impl<0>(node, gs, bs, gv, Wss, Wvs, Wsd, Wvd, ssrc, sdst, vsrc, vdst,
                     shs[wv], shv[wv], n, lane);
}

// ---------------- Kernel 2: fused MFMA edge pass over dst-sorted edges ----------------
// LDS per wave (bf16 elems): A1S [16][104]; A1V 3x[16][136]; VAL [16][72]
// After S7, H is reused as fp32 [16][168] for the segmented dst-reduction.
static constexpr int A1S = 0,    SS = 104;
static constexpr int A1V = 1664, PV = 2176, SV = 136;
static constexpr int VAL = 8192, SA = 72;
static constexpr int HSZ = 9344;

__global__ __launch_bounds__(256, 2) void k_edge(
    const void* __restrict__ eidx, const void* __restrict__ rbf, const void* __restrict__ rsh,
    const bf16* __restrict__ WalphaT, const bf16* __restrict__ WsvalT, const bf16* __restrict__ WsvlinT,
    const bf16* __restrict__ WvvalT, const bf16* __restrict__ WvvlinT, const bf16* __restrict__ WgT,
    const bf16* __restrict__ WrbfT, const bf16* __restrict__ adotB, const bf16* __restrict__ w2B,
    const bf16* __restrict__ ssrc, const bf16* __restrict__ sdst,
    const bf16* __restrict__ vsrc, const bf16* __restrict__ vdst,
    const int* __restrict__ perm,
    float* __restrict__ den, float* __restrict__ agg,
    const int* __restrict__ flags, int E)
{
    const int bfm = flags[0];
    const int i64 = flags[1];

    __shared__ __align__(16) __bf16 sH[4][HSZ];
    __shared__ __align__(16) float sRbf[4][16][20];
    __shared__ __align__(16) float sY[4][16][4];
    __shared__ int sSD[4][48];   // [0..15]=src, [16..31]=dst, [32..47]=permuted edge id

    int wv = threadIdx.x >> 6, l = threadIdx.x & 63;
    int q = l >> 4, m = l & 15;
    long long eb = ((long long)blockIdx.x * 4 + wv) * 16;
    if (eb >= E) return;        // wave-uniform; no barriers in this kernel
    __bf16* H = &sH[wv][0];

    // ---- edge metadata (sorted position -> edge id via perm) ----
    if (l < 16) {
        long long p = eb + l; if (p > (long long)E - 1) p = E - 1;
        sSD[wv][32 + l] = perm[p];
    }
    if (l < 32) {
        int pe = sSD[wv][32 + (l & 15)];
        long long off = (l < 16) ? (long long)pe : ((long long)E + pe);
        sSD[wv][l] = i64 ? (int)((const long long*)eidx)[off] : ((const int*)eidx)[off];
    }
    {
        int pe = sSD[wv][32 + (l >> 2)];
        sY[wv][l >> 2][l & 3] = ldr(rsh, (size_t)pe * 4 + (l & 3), bfm);
    }
    #pragma unroll
    for (int j = 0; j < 4; ++j) {
        int pe = sSD[wv][32 + j * 4 + q];
        sRbf[wv][m][j * 4 + q] = ldr(rbf, (size_t)pe * 16 + m, bfm);
    }

    // ---- WrbfT fragments ----
    const __bf16* wrt = (const __bf16*)WrbfT;
    int lv = l & 31;
    bfv8 w0a = *(const bfv8*)(wrt + l * 16);
    bfv8 w0b = *(const bfv8*)(wrt + l * 16 + 8);
    bfv8 w1a = *(const bfv8*)(wrt + (64 + l) * 16);
    bfv8 w1b = *(const bfv8*)(wrt + (64 + l) * 16 + 8);
    bfv8 w2a = *(const bfv8*)(wrt + (128 + lv) * 16);
    bfv8 w2b = *(const bfv8*)(wrt + (128 + lv) * 16 + 8);
    bfv8 w3a = *(const bfv8*)(wrt + (160 + lv) * 16);
    bfv8 w3b = *(const bfv8*)(wrt + (160 + lv) * 16 + 8);
    bfv8 w4a = *(const bfv8*)(wrt + (192 + lv) * 16);
    bfv8 w4b = *(const bfv8*)(wrt + (192 + lv) * 16 + 8);

    // ---- S1: gather + w1 + m1 tensor product -> LDS ----
    #pragma unroll 1
    for (int h = 0; h < 2; ++h) {
        bf16 rS[8], rD[8], rv[6][8];
        #pragma unroll
        for (int k = 0; k < 8; ++k) {
            int s = sSD[wv][8 * h + k], d = sSD[wv][16 + 8 * h + k];
            rS[k] = ssrc[(size_t)s * 64 + l];
            rD[k] = sdst[(size_t)d * 64 + l];
            if (l < 32) {
                rv[0][k] = vsrc[(size_t)s * 96 +      l];
                rv[1][k] = vsrc[(size_t)s * 96 + 32 + l];
                rv[2][k] = vsrc[(size_t)s * 96 + 64 + l];
                rv[3][k] = vdst[(size_t)d * 96 +      l];
                rv[4][k] = vdst[(size_t)d * 96 + 32 + l];
                rv[5][k] = vdst[(size_t)d * 96 + 64 + l];
            }
        }
        #pragma unroll
        for (int j2 = 0; j2 < 2; ++j2) {
            int jj = 2 * h + j2;
            float y0k[4], yxk[4], yyk[4], yzk[4], ms[4];
            float mv0[4], mv1[4], mv2[4];
            #pragma unroll
            for (int k = 0; k < 4; ++k) {
                float4 yy = *(const float4*)&sY[wv][4 * jj + k][0];
                y0k[k] = yy.x; yxk[k] = yy.y; yyk[k] = yy.z; yzk[k] = yy.w;
                int kk = 4 * j2 + k;
                ms[k]  = b2f(rS[kk]) + b2f(rD[kk]);
                mv0[k] = b2f(rv[0][kk]) + b2f(rv[3][kk]);
                mv1[k] = b2f(rv[1][kk]) + b2f(rv[4][kk]);
                mv2[k] = b2f(rv[2][kk]) + b2f(rv[5][kk]);
            }
            float wss[4] = {0,0,0,0}, wsv[4] = {0,0,0,0};
            float wvs[4] = {0,0,0,0}, wv0[4] = {0,0,0,0}, wv1[4] = {0,0,0,0};
            #pragma unroll
            for (int b = 0; b < 16; ++b) {
                float2 ra = *(const float2*)&sRbf[wv][b][4 * jj];
                float2 rb = *(const float2*)&sRbf[wv][b][4 * jj + 2];
                float r0 = ra.x, r1 = ra.y, r2 = rb.x, r3 = rb.y;
                float wa  = (float)(b < 8 ? w0a[b] : w0b[b - 8]);
                float wb_ = (float)(b < 8 ? w1a[b] : w1b[b - 8]);
                float wc  = (float)(b < 8 ? w2a[b] : w2b[b - 8]);
                float wd  = (float)(b < 8 ? w3a[b] : w3b[b - 8]);
                float we  = (float)(b < 8 ? w4a[b] : w4b[b - 8]);
                wss[0] += r0 * wa;  wss[1] += r1 * wa;  wss[2] += r2 * wa;  wss[3] += r3 * wa;
                wsv[0] += r0 * wb_; wsv[1] += r1 * wb_; wsv[2] += r2 * wb_; wsv[3] += r3 * wb_;
                wvs[0] += r0 * wc;  wvs[1] += r1 * wc;  wvs[2] += r2 * wc;  wvs[3] += r3 * wc;
                wv0[0] += r0 * wd;  wv0[1] += r1 * wd;  wv0[2] += r2 * wd;  wv0[3] += r3 * wd;
                wv1[0] += r0 * we;  wv1[1] += r1 * we;  wv1[2] += r2 * we;  wv1[3] += r3 * we;
            }
            #pragma unroll
            for (int k = 0; k < 4; ++k) {
                int e = 4 * jj + k;
                H[A1S + e * SS + l] = (__bf16)(wss[k] * ms[k] * y0k[k]);
                float sv = wsv[k] * ms[k];
                H[A1V + 0 * PV + e * SV + l] = (__bf16)(sv * yxk[k]);
                H[A1V + 1 * PV + e * SV + l] = (__bf16)(sv * yyk[k]);
                H[A1V + 2 * PV + e * SV + l] = (__bf16)(sv * yzk[k]);
            }
            if (l < 32) {
                #pragma unroll
                for (int k = 0; k < 4; ++k) {
                    int e = 4 * jj + k;
                    H[A1S + e * SS + 64 + l] =
                        (__bf16)(wv0[k] * (mv0[k] * yxk[k] + mv1[k] * yyk[k] + mv2[k] * yzk[k]) * SQRT3_INV);
                    H[A1V + 0 * PV + e * SV + 64 + l] = (__bf16)(wvs[k] * mv0[k] * y0k[k]);
                    H[A1V + 1 * PV + e * SV + 64 + l] = (__bf16)(wvs[k] * mv1[k] * y0k[k]);
                    H[A1V + 2 * PV + e * SV + 64 + l] = (__bf16)(wvs[k] * mv2[k] * y0k[k]);
                    float cx = mv1[k] * yzk[k] - mv2[k] * yyk[k];
                    float cy = mv2[k] * yxk[k] - mv0[k] * yzk[k];
                    float cz = mv0[k] * yyk[k] - mv1[k] * yxk[k];
                    H[A1V + 0 * PV + e * SV + 96 + l] = (__bf16)(wv1[k] * cx * SQRT2_INV);
                    H[A1V + 1 * PV + e * SV + 96 + l] = (__bf16)(wv1[k] * cy * SQRT2_INV);
                    H[A1V + 2 * PV + e * SV + 96 + l] = (__bf16)(wv1[k] * cz * SQRT2_INV);
                }
            }
        }
    }

    const int kq = q * 8;

    // ---- S2: val_s = m1_s @ Ws_val; PRE-sigmoid -> VAL, sigmoid -> regs ----
    bfv8 a1s0 = *(const bfv8*)(H + A1S + m * SS + 0  + kq);
    bfv8 a1s1 = *(const bfv8*)(H + A1S + m * SS + 32 + kq);
    bfv8 a1s2 = *(const bfv8*)(H + A1S + m * SS + 64 + kq);
    f4 vals[4];
    #pragma unroll
    for (int nt = 0; nt < 4; ++nt) {
        const __bf16* bp = (const __bf16*)WsvalT + (size_t)(nt * 16 + m) * 96 + kq;
        f4 acc = {0.f, 0.f, 0.f, 0.f};
        acc = mf(a1s0, *(const bfv8*)(bp),      acc);
        acc = mf(a1s1, *(const bfv8*)(bp + 32), acc);
        acc = mf(a1s2, *(const bfv8*)(bp + 64), acc);
        vals[nt] = acc;
    }
    #pragma unroll
    for (int nt = 0; nt < 4; ++nt)
        #pragma unroll
        for (int r = 0; r < 4; ++r) {
            float v = vals[nt][r];
            H[VAL + (q * 4 + r) * SA + nt * 16 + m] = (__bf16)v;   // PRE-sigmoid
            vals[nt][r] = 1.f / (1.f + __expf(-v));
        }

    // ---- S3: gate = sigmoid(val_s_pre @ Wg) ----
    bfv8 av0 = *(const bfv8*)(H + VAL + m * SA + 0  + kq);
    bfv8 av1 = *(const bfv8*)(H + VAL + m * SA + 32 + kq);
    f4 gate[2];
    #pragma unroll
    for (int nt = 0; nt < 2; ++nt) {
        const __bf16* bp = (const __bf16*)WgT + (size_t)(nt * 16 + m) * 64 + kq;
        f4 acc = {0.f, 0.f, 0.f, 0.f};
        acc = mf(av0, *(const bfv8*)(bp),      acc);
        acc = mf(av1, *(const bfv8*)(bp + 32), acc);
        gate[nt] = acc;
    }
    #pragma unroll
    for (int nt = 0; nt < 2; ++nt)
        #pragma unroll
        for (int r = 0; r < 4; ++r)
            gate[nt][r] = 1.f / (1.f + __expf(-gate[nt][r]));

    // ---- S4: attention logits + ex (den-restructured softmax) ----
    float ex_[4][4];
    #pragma unroll
    for (int nt = 0; nt < 4; ++nt) {
        const __bf16* bp = (const __bf16*)WalphaT + (size_t)(nt * 16 + m) * 96 + kq;
        f4 acc = {0.f, 0.f, 0.f, 0.f};
        acc = mf(a1s0, *(const bfv8*)(bp),      acc);
        acc = mf(a1s1, *(const bfv8*)(bp + 32), acc);
        acc = mf(a1s2, *(const bfv8*)(bp + 64), acc);
        float ad = b2f(adotB[nt * 16 + m]);
        #pragma unroll
        for (int r = 0; r < 4; ++r) {
            float tv = acc[r];
            tv = tv > 0.f ? tv : 0.2f * tv;
            tv *= ad;
            tv += __shfl_xor(tv, 1); tv += __shfl_xor(tv, 2);
            tv += __shfl_xor(tv, 4); tv += __shfl_xor(tv, 8);
            tv = fminf(fmaxf(tv, -60.f), 60.f);
            ex_[nt][r] = __expf(tv);
        }
    }

    // ---- S5: val_v = (m1_v @ Wv_val) * gate ----
    bfv8 a1v[3][4];
    #pragma unroll
    for (int x = 0; x < 3; ++x)
        #pragma unroll
        for (int kt = 0; kt < 4; ++kt)
            a1v[x][kt] = *(const bfv8*)(H + A1V + x * PV + m * SV + kt * 32 + kq);
    f4 vv[3][2];
    #pragma unroll
    for (int x = 0; x < 3; ++x)
        #pragma unroll
        for (int nt = 0; nt < 2; ++nt)
            vv[x][nt] = (f4){0.f, 0.f, 0.f, 0.f};
    #pragma unroll
    for (int nt = 0; nt < 2; ++nt) {
        const __bf16* bp = (const __bf16*)WvvalT + (size_t)(nt * 16 + m) * 128 + kq;
        #pragma unroll
        for (int kt = 0; kt < 4; ++kt) {
            bfv8 b = *(const bfv8*)(bp + kt * 32);
            vv[0][nt] = mf(a1v[0][kt], b, vv[0][nt]);
            vv[1][nt] = mf(a1v[1][kt], b, vv[1][nt]);
            vv[2][nt] = mf(a1v[2][kt], b, vv[2][nt]);
        }
    }
    #pragma unroll
    for (int x = 0; x < 3; ++x)
        #pragma unroll
        for (int nt = 0; nt < 2; ++nt)
            #pragma unroll
            for (int r = 0; r < 4; ++r)
                vv[x][nt][r] *= gate[nt][r];

    // ---- S6: m2 tensor product -> LDS (reuse m1 buffers) ----
    float c2ss[4], c2sv[4];
    #pragma unroll
    for (int nt = 0; nt < 4; ++nt) {
        c2ss[nt] = b2f(w2B[nt * 16 + m]);
        c2sv[nt] = b2f(w2B[64 + nt * 16 + m]);
    }
    float c2vs[2], c2v0[2], c2v1[2];
    #pragma unroll
    for (int nt = 0; nt < 2; ++nt) {
        c2vs[nt] = b2f(w2B[128 + nt * 16 + m]);
        c2v0[nt] = b2f(w2B[160 + nt * 16 + m]);
        c2v1[nt] = b2f(w2B[192 + nt * 16 + m]);
    }
    #pragma unroll
    for (int r = 0; r < 4; ++r) {
        int e = q * 4 + r;
        float4 yy = *(const float4*)&sY[wv][e][0];
        float y0 = yy.x, yx = yy.y, yh = yy.z, yz = yy.w;
        int rS  = A1S + e * SS;
        int rV0 = A1V + 0 * PV + e * SV;
        int rV1 = A1V + 1 * PV + e * SV;
        int rV2 = A1V + 2 * PV + e * SV;
        #pragma unroll
        for (int nt = 0; nt < 4; ++nt) {
            int c = nt * 16 + m;
            float va = vals[nt][r];
            H[rS + c] = (__bf16)(c2ss[nt] * va * y0);
            float t2 = c2sv[nt] * va;
            H[rV0 + c] = (__bf16)(t2 * yx);
            H[rV1 + c] = (__bf16)(t2 * yh);
            H[rV2 + c] = (__bf16)(t2 * yz);
        }
        #pragma unroll
        for (int nt = 0; nt < 2; ++nt) {
            int c = nt * 16 + m;
            float v0 = vv[0][nt][r], v1 = vv[1][nt][r], v2 = vv[2][nt][r];
            H[rS + 64 + c] = (__bf16)(c2v0[nt] * (v0 * yx + v1 * yh + v2 * yz) * SQRT3_INV);
            H[rV0 + 64 + c] = (__bf16)(c2vs[nt] * v0 * y0);
            H[rV1 + 64 + c] = (__bf16)(c2vs[nt] * v1 * y0);
            H[rV2 + 64 + c] = (__bf16)(c2vs[nt] * v2 * y0);
            float cx = v1 * yz - v2 * yh;
            float cy = v2 * yx - v0 * yz;
            float cz = v0 * yh - v1 * yx;
            H[rV0 + 96 + c] = (__bf16)(c2v1[nt] * cx * SQRT2_INV);
            H[rV1 + 96 + c] = (__bf16)(c2v1[nt] * cy * SQRT2_INV);
            H[rV2 + 96 + c] = (__bf16)(c2v1[nt] * cz * SQRT2_INV);
        }
    }

    // ---- S7: h projections ----
    bfv8 a2s0 = *(const bfv8*)(H + A1S + m * SS + 0  + kq);
    bfv8 a2s1 = *(const bfv8*)(H + A1S + m * SS + 32 + kq);
    bfv8 a2s2 = *(const bfv8*)(H + A1S + m * SS + 64 + kq);
    f4 hs[4];
    #pragma unroll
    for (int nt = 0; nt < 4; ++nt) {
        const __bf16* bp = (const __bf16*)WsvlinT + (size_t)(nt * 16 + m) * 96 + kq;
        f4 acc = {0.f, 0.f, 0.f, 0.f};
        acc = mf(a2s0, *(const bfv8*)(bp),      acc);
        acc = mf(a2s1, *(const bfv8*)(bp + 32), acc);
        acc = mf(a2s2, *(const bfv8*)(bp + 64), acc);
        hs[nt] = acc;
    }
    bfv8 a2v[3][4];
    #pragma unroll
    for (int x = 0; x < 3; ++x)
        #pragma unroll
        for (int kt = 0; kt < 4; ++kt)
            a2v[x][kt] = *(const bfv8*)(H + A1V + x * PV + m * SV + kt * 32 + kq);
    f4 hv[3][2];
    #pragma unroll
    for (int x = 0; x < 3; ++x)
        #pragma unroll
        for (int nt = 0; nt < 2; ++nt)
            hv[x][nt] = (f4){0.f, 0.f, 0.f, 0.f};
    #pragma unroll
    for (int nt = 0; nt < 2; ++nt) {
        const __bf16* bp = (const __bf16*)WvvlinT + (size_t)(nt * 16 + m) * 128 + kq;
        #pragma unroll
        for (int kt = 0; kt < 4; ++kt) {
            bfv8 b = *(const bfv8*)(bp + kt * 32);
            hv[0][nt] = mf(a2v[0][kt], b, hv[0][nt]);
            hv[1][nt] = mf(a2v[1][kt], b, hv[1][nt]);
            hv[2][nt] = mf(a2v[2][kt], b, hv[2][nt]);
        }
    }

    // ---- S8: in-wave segmented reduction over sorted dst, then few atomics ----
    // Reuse H as fp32 [16][168]: ch 0..159 = agg row, 160..163 = den (ex per head).
    float* Hf = (float*)H;
    #pragma unroll
    for (int r = 0; r < 4; ++r) {
        int e = q * 4 + r;
        float* row = Hf + e * 168;
        #pragma unroll
        for (int nt = 0; nt < 4; ++nt)
            row[nt * 40 + m] = ex_[nt][r] * hs[nt][r];
        #pragma unroll
        for (int nt = 0; nt < 2; ++nt) {
            int c = nt * 16 + m;
            int hh = c >> 3, dd = c & 7;
            float exv = (m >= 8) ? ex_[2 * nt + 1][r] : ex_[2 * nt][r];
            float* vb = row + hh * 40 + 16 + dd * 3;
            vb[0] = exv * hv[0][nt][r];
            vb[1] = exv * hv[1][nt][r];
            vb[2] = exv * hv[2][nt][r];
        }
        if (m < 4) row[160 + m] = ex_[m][r];
    }
    // same-wave LDS ordering: writes above retire before reads below
    int nval = (int)((E - eb) < 16 ? (E - eb) : 16);
    {
        int s = 0;
        while (s < nval) {
            int d = sSD[wv][16 + s];
            int t = s + 1;
            while (t < nval && sSD[wv][16 + t] == d) ++t;
            float s0 = 0.f, s1 = 0.f, s2 = 0.f;
            for (int e = s; e < t; ++e) {
                const float* row = Hf + e * 168;
                s0 += row[l];
                s1 += row[64 + l];
                if (l < 36) s2 += row[128 + l];
            }
            float* rowp = agg + (size_t)d * 160;
            unsafeAtomicAdd(rowp + l, s0);
            unsafeAtomicAdd(rowp + 64 + l, s1);
            if (l < 32)      unsafeAtomicAdd(rowp + 128 + l, s2);
            else if (l < 36) unsafeAtomicAdd(den + (size_t)d * 4 + (l - 32), s2);
            s = t;
        }
    }
}

// ---------------- Kernel 3: normalize + output projection + residual (4 nodes/block) ----------------
template<int BF>
__device__ __forceinline__ void out_impl(
    const void* node, const float* den, const float* agg,
    const void* Wps, const void* Wpv, void* out,
    float* shs, float* shv, float* sinv, int n, int lane)
{
    if (lane < 4) sinv[lane] = 1.f / (den[(size_t)n * 4 + lane] + 1e-16f);
    for (int idx = lane; idx < 160; idx += 64) {
        int h = idx / 40, r = idx - h * 40;
        float val = agg[(size_t)n * 160 + idx] * sinv[h];
        if (r < 16) shs[h * 16 + r] = val;
        else { int rr = r - 16; int dd = rr / 3, x = rr - dd * 3; shv[x * 32 + h * 8 + dd] = val; }
    }

    float acc = ldf<BF>(node, (size_t)n * 160 + lane);
    for (int c = 0; c < 64; ++c) acc += shs[c] * ldf<BF>(Wps, c * 64 + lane);
    stf<BF>(out, (size_t)n * 160 + lane, acc);

    {
        int idx = lane; int dd = idx / 3, x = idx - dd * 3;
        float a = ldf<BF>(node, (size_t)n * 160 + 64 + idx);
        for (int c = 0; c < 32; ++c) a += shv[x * 32 + c] * ldf<BF>(Wpv, c * 32 + dd);
        stf<BF>(out, (size_t)n * 160 + 64 + idx, a);
    }
    if (lane < 32) {
        int idx = 64 + lane; int dd = idx / 3, x = idx - dd * 3;
        float a = ldf<BF>(node, (size_t)n * 160 + 64 + idx);
        for (int c = 0; c < 32; ++c) a += shv[x * 32 + c] * ldf<BF>(Wpv, c * 32 + dd);
        stf<BF>(out, (size_t)n * 160 + 64 + idx, a);
    }
}

__global__ __launch_bounds__(256) void k_out(
    const void* node, const float* den, const float* agg,
    const void* Wps, const void* Wpv, void* out,
    const int* flags, int N)
{
    __shared__ float shs[4][64];
    __shared__ float shv[4][96];
    __shared__ float sinv[4][4];
    int wv = threadIdx.x >> 6, lane = threadIdx.x & 63;
    int n = blockIdx.x * 4 + wv; if (n >= N) return;
    if (flags[0])
        out_impl<1>(node, den, agg, Wps, Wpv, out, shs[wv], shv[wv], sinv[wv], n, lane);
    else
        out_impl<0>(node, den, agg, Wps, Wpv, out, shs[wv], shv[wv], sinv[wv], n, lane);
}

// ---------------- Launch ----------------
extern "C" void kernel_launch(void* const* d_in, const int* in_sizes, int n_in,
                              void* d_out, int out_size, void* d_ws, size_t ws_size,
                              hipStream_t stream)
{
    const void* node   = d_in[0];
    const void* eidx   = d_in[1];
    const void* rbf    = d_in[2];
    const void* rsh    = d_in[3];
    const void* gs     = d_in[4];
    const void* bs     = d_in[5];
    const void* gv     = d_in[6];
    const void* Wss    = d_in[7];
    const void* Wvs    = d_in[8];
    const void* Wsd    = d_in[9];
    const void* Wvd    = d_in[10];
    const void* Wrbf   = d_in[11];
    const void* Walpha = d_in[12];
    const void* adot   = d_in[13];
    const void* Wsval  = d_in[14];
    const void* Wvval  = d_in[15];
    const void* Wg     = d_in[16];
    const void* w2ss   = d_in[17];
    const void* w2sv   = d_in[18];
    const void* w2vs   = d_in[19];
    const void* w2vv0  = d_in[20];
    const void* w2vv1  = d_in[21];
    const void* Wsvlin = d_in[22];
    const void* Wvvlin = d_in[23];
    const void* Wps    = d_in[24];
    const void* Wpv    = d_in[25];

    int N = in_sizes[0] / 160;
    int E = in_sizes[1] / 2;

    char* base = (char*)d_ws;
    int*  flags   = (int*)base;                  // 16 B
    bf16* WalphaT = (bf16*)(base + 16);
    bf16* WsvalT  = WalphaT + 6144;
    bf16* WsvlinT = WsvalT  + 6144;
    bf16* WvvalT  = WsvlinT + 6144;
    bf16* WvvlinT = WvvalT  + 4096;
    bf16* WgT     = WvvlinT + 4096;
    bf16* WrbfT   = WgT     + 2048;
    bf16* adotB   = WrbfT   + 3584;
    bf16* w2B     = adotB   + 64;
    bf16* ssrc    = w2B     + 224;
    bf16* sdst    = ssrc + (size_t)N * 64;
    bf16* vsrc    = sdst + (size_t)N * 64;
    bf16* vdst    = vsrc + (size_t)N * 96;
    float* den    = (float*)(vdst + (size_t)N * 96);
    float* agg    = den + (size_t)N * 4;
    int*  cnt     = (int*)(agg + (size_t)N * 160);
    int*  perm    = cnt + N;

    k_sniff<<<1, 256, 0, stream>>>(node, eidx, flags);
    int zn = N * 164;
    k_zero<<<(zn + 255) / 256, 256, 0, stream>>>(den, zn);
    k_zero<<<(N + 255) / 256, 256, 0, stream>>>((float*)cnt, N);   // zero bits == int 0

    // counting sort of edges by dst
    int nbe = (E + 255) / 256;
    k_hist<<<nbe, 256, 0, stream>>>(eidx, cnt, flags, E);
    k_scan<<<1, 256, 0, stream>>>(cnt, N);
    k_perm<<<nbe, 256, 0, stream>>>(eidx, cnt, perm, flags, E);

    k_prep<<<16, 256, 0, stream>>>(Walpha, Wsval, Wsvlin, Wvval, Wvvlin, Wg, Wrbf, adot,
                                   w2ss, w2sv, w2vs, w2vv0, w2vv1,
                                   WalphaT, WsvalT, WsvlinT, WvvalT, WvvlinT, WgT, WrbfT,
                                   adotB, w2B, flags);

    int nbn = (N + 3) / 4;
    k_node<<<nbn, 256, 0, stream>>>(node, gs, bs, gv, Wss, Wvs, Wsd, Wvd,
                                    ssrc, sdst, vsrc, vdst, flags, N);

    int nb = (E + 63) / 64;
    k_edge<<<nb, 256, 0, stream>>>(eidx, rbf, rsh,
                                   WalphaT, WsvalT, WsvlinT, WvvalT, WvvlinT, WgT, WrbfT,
                                   adotB, w2B, ssrc, sdst, vsrc, vdst, perm, den, agg, flags, E);

    int nbo = (N + 3) / 4;
    k_out<<<nbo, 256, 0, stream>>>(node, den, agg, Wps, Wpv, d_out, flags, N);
}